// Round 1
// baseline (1547.793 us; speedup 1.0000x reference)
//
#include <hip/hip_runtime.h>
#include <cstdint>
#include <cstddef>

// Problem constants (fixed by reference file)
#define NB_N 100000
#define E_N  131072
#define T_N  16384
#define D_N  512
#define NCLS 40

typedef unsigned short u16;
typedef unsigned int   u32;
typedef __attribute__((ext_vector_type(8))) short  short8;   // 8 bf16 (4 VGPRs)
typedef __attribute__((ext_vector_type(4))) float  floatx4;  // MFMA accumulator

// ---------- bf16 helpers (manual, RNE) ----------
__device__ __forceinline__ u16 f2bf(float f) {
  u32 u = __float_as_uint(f);
  return (u16)((u + 0x7fffu + ((u >> 16) & 1u)) >> 16);
}
__device__ __forceinline__ void unpack8(uint4 z, float* f) {
  f[0] = __uint_as_float(z.x << 16);
  f[1] = __uint_as_float(z.x & 0xffff0000u);
  f[2] = __uint_as_float(z.y << 16);
  f[3] = __uint_as_float(z.y & 0xffff0000u);
  f[4] = __uint_as_float(z.z << 16);
  f[5] = __uint_as_float(z.z & 0xffff0000u);
  f[6] = __uint_as_float(z.w << 16);
  f[7] = __uint_as_float(z.w & 0xffff0000u);
}
__device__ __forceinline__ void gload_lds16(const void* g, void* s) {
  __builtin_amdgcn_global_load_lds(
      (const __attribute__((address_space(1))) unsigned int*)g,
      (__attribute__((address_space(3))) unsigned int*)s, 16, 0, 0);
}

// ---------- kernel 0: transpose+convert pca_w (K,N) f32 -> Bt (N,K) bf16 ----------
__global__ void conv_bt(const float* __restrict__ w, u16* __restrict__ Bt) {
  int i = blockIdx.x * 256 + threadIdx.x;       // i over 512*512, i = n*512+k
  int n = i >> 9, k = i & 511;
  Bt[i] = f2bf(w[k * 512 + n]);
}

// ---------- kernel 1: CSR offsets from sorted row_idx ----------
__global__ void build_offs(const int* __restrict__ rowi, int* __restrict__ offs) {
  int e = blockIdx.x * 256 + threadIdx.x;
  if (e >= E_N) return;
  int r  = rowi[e];
  int rp = (e == 0) ? -1 : rowi[e - 1];
  for (int t = rp + 1; t <= r; ++t) offs[t] = e;
  if (e == E_N - 1)
    for (int t = r + 1; t <= T_N; ++t) offs[t] = E_N;
}

// ---------- kernel 2: segment softmax of ppr ----------
__global__ void ppr_sm(const float* __restrict__ ppr, const int* __restrict__ offs,
                       float* __restrict__ pprn) {
  int t = blockIdx.x * 256 + threadIdx.x;       // T_N threads
  int s = offs[t], en = offs[t + 1];
  if (s >= en) return;
  float m = -INFINITY;
  for (int e = s; e < en; ++e) m = fmaxf(m, ppr[e]);
  float sum = 0.f;
  for (int e = s; e < en; ++e) sum += expf(ppr[e] - m);
  float inv = 1.f / sum;
  for (int e = s; e < en; ++e) pprn[e] = expf(ppr[e] - m) * inv;
}

// ---------- kernel 3: bf16 MFMA GEMM x = relu(x_nb @ pca_w + b), per-capsule l2norm,
//            writes xn bf16 (NB, 512). 128x128 tile, BK=64, 4 waves. ----------
__global__ __launch_bounds__(256) void gemm_pca(
    const float* __restrict__ A,    // x_nb (NB,512) f32
    const u16*   __restrict__ Bt,   // (512,512) bf16, n-major (pre-transposed)
    const float* __restrict__ bias, // (512,)
    u16*         __restrict__ xn) { // (NB,512) bf16, normalized
  __shared__ u16 As[128 * 64];      // 16 KB
  __shared__ u16 Bs[128 * 64];      // 16 KB
  const int tid  = threadIdx.x;
  const int wid  = tid >> 6, lane = tid & 63;
  const int quad = lane >> 4, l16 = lane & 15;
  const int m0 = blockIdx.y * 128;
  const int n0 = blockIdx.x * 128;
  const int wm = (wid >> 1) * 64;   // wave tile origin within block
  const int wn = (wid & 1) * 64;

  floatx4 acc[4][4];
#pragma unroll
  for (int i = 0; i < 4; ++i)
#pragma unroll
    for (int j = 0; j < 4; ++j) acc[i][j] = (floatx4){0.f, 0.f, 0.f, 0.f};

  for (int k0 = 0; k0 < 512; k0 += 64) {
    // stage A (128 rows x 64 k) f32 -> bf16 in LDS, zero-pad rows >= NB
#pragma unroll
    for (int j = 0; j < 8; ++j) {
      int ci  = j * 256 + tid;      // 2048 float4 chunks
      int row = ci >> 4, c4 = ci & 15;
      int gm  = m0 + row;
      float4 va;
      if (gm < NB_N) va = *(const float4*)(A + (size_t)gm * 512 + k0 + (c4 << 2));
      else           va = make_float4(0.f, 0.f, 0.f, 0.f);
      uint2 pk;
      pk.x = (u32)f2bf(va.x) | ((u32)f2bf(va.y) << 16);
      pk.y = (u32)f2bf(va.z) | ((u32)f2bf(va.w) << 16);
      *(uint2*)(&As[(row << 6) + (c4 << 2)]) = pk;
    }
    // stage B via async global->LDS (16B/lane, wave-uniform LDS base + lane*16)
#pragma unroll
    for (int j = 0; j < 4; ++j) {
      int ci  = j * 256 + wid * 64 + lane;  // 16B chunk id, 1024 total
      int row = ci >> 3, kc = ci & 7;
      const void* g = (const void*)(Bt + (size_t)(n0 + row) * 512 + k0 + kc * 8);
      void* s = (void*)(&Bs[(size_t)(j * 256 + wid * 64) * 8]);
      gload_lds16(g, s);
    }
    __syncthreads();
#pragma unroll
    for (int kk = 0; kk < 64; kk += 32) {
      short8 af[4], bf[4];
#pragma unroll
      for (int mi = 0; mi < 4; ++mi)
        af[mi] = *(const short8*)(&As[(wm + mi * 16 + l16) * 64 + kk + quad * 8]);
#pragma unroll
      for (int ni = 0; ni < 4; ++ni)
        bf[ni] = *(const short8*)(&Bs[(wn + ni * 16 + l16) * 64 + kk + quad * 8]);
#pragma unroll
      for (int mi = 0; mi < 4; ++mi)
#pragma unroll
        for (int ni = 0; ni < 4; ++ni)
          acc[mi][ni] = __builtin_amdgcn_mfma_f32_16x16x32_bf16(af[mi], bf[ni],
                                                                acc[mi][ni], 0, 0, 0);
    }
    __syncthreads();
  }

  // epilogue: +bias, relu, per-capsule (64-col) l2norm, store bf16.
  // C/D layout: col = lane&15 (n), row = quad*4 + reg (within 16-row tile).
  // wave covers 64 cols = exactly one capsule -> reduce over 4 ni x 16 lanes.
#pragma unroll
  for (int mi = 0; mi < 4; ++mi) {
#pragma unroll
    for (int r = 0; r < 4; ++r) {
      int gm = m0 + wm + mi * 16 + quad * 4 + r;
      float v[4];
      float ss = 0.f;
#pragma unroll
      for (int ni = 0; ni < 4; ++ni) {
        int n  = n0 + wn + ni * 16 + l16;
        float x = acc[mi][ni][r] + bias[n];
        x = fmaxf(x, 0.f);
        v[ni] = x;
        ss += x * x;
      }
      ss += __shfl_xor(ss, 1);
      ss += __shfl_xor(ss, 2);
      ss += __shfl_xor(ss, 4);
      ss += __shfl_xor(ss, 8);
      float sc = 1.f / fmaxf(sqrtf(ss), 1e-12f);
      if (gm < NB_N) {
#pragma unroll
        for (int ni = 0; ni < 4; ++ni) {
          int n = n0 + wn + ni * 16 + l16;
          xn[(size_t)gm * 512 + n] = f2bf(v[ni] * sc);
        }
      }
    }
  }
}

// ---------- kernel 4: u[t] = sum_e w_e * z_e (wave per target; optional capsule l2norm) ----
__global__ __launch_bounds__(256) void scatter_u(
    const u16* __restrict__ xn, const int* __restrict__ coli,
    const int* __restrict__ offs, const float* __restrict__ we,
    int init, int do_norm, float* __restrict__ u) {
  int wid = threadIdx.x >> 6, lane = threadIdx.x & 63;
  int t = blockIdx.x * 4 + wid;
  int s = offs[t], en = offs[t + 1];
  int cap = lane >> 3;                   // capsule of this lane's 8 dims
  float acc[8] = {0.f, 0.f, 0.f, 0.f, 0.f, 0.f, 0.f, 0.f};
  for (int e = s; e < en; ++e) {
    float w = init ? we[e] : we[(size_t)e * 8 + cap];
    uint4 zz = *(const uint4*)(xn + (size_t)coli[e] * 512 + lane * 8);
    float zf[8];
    unpack8(zz, zf);
#pragma unroll
    for (int j = 0; j < 8; ++j) acc[j] += w * zf[j];
  }
  if (do_norm) {
    float ss = 0.f;
#pragma unroll
    for (int j = 0; j < 8; ++j) ss += acc[j] * acc[j];
    ss += __shfl_xor(ss, 1);
    ss += __shfl_xor(ss, 2);
    ss += __shfl_xor(ss, 4);
    float sc = 1.f / fmaxf(sqrtf(ss), 1e-12f);
#pragma unroll
    for (int j = 0; j < 8; ++j) acc[j] *= sc;
  }
  float* ur = u + (size_t)t * 512 + lane * 8;
  *(float4*)(ur)     = make_float4(acc[0], acc[1], acc[2], acc[3]);
  *(float4*)(ur + 4) = make_float4(acc[4], acc[5], acc[6], acc[7]);
}

// ---------- kernel 5: per-edge capsule logits p[e][k] = <u[row_e]_k, z_e_k> ----------
__global__ __launch_bounds__(256) void edge_logits(
    const u16* __restrict__ xn, const float* __restrict__ u,
    const int* __restrict__ rowi, const int* __restrict__ coli,
    float* __restrict__ p) {
  int wid = threadIdx.x >> 6, lane = threadIdx.x & 63;
  int e = blockIdx.x * 4 + wid;
  int r = rowi[e], c = coli[e];
  uint4 zz = *(const uint4*)(xn + (size_t)c * 512 + lane * 8);
  float zf[8];
  unpack8(zz, zf);
  const float* ur = u + (size_t)r * 512 + lane * 8;
  float4 u0 = *(const float4*)(ur);
  float4 u1 = *(const float4*)(ur + 4);
  float s = u0.x * zf[0] + u0.y * zf[1] + u0.z * zf[2] + u0.w * zf[3] +
            u1.x * zf[4] + u1.y * zf[5] + u1.z * zf[6] + u1.w * zf[7];
  s += __shfl_xor(s, 1);
  s += __shfl_xor(s, 2);
  s += __shfl_xor(s, 4);
  if ((lane & 7) == 0) p[(size_t)e * 8 + (lane >> 3)] = s;
}

// ---------- kernel 6: p = segsm(p); p = 0.5*p + 0.5*pprn; p = segsm(p). thread per (t,k) ----
__global__ void seg_sm2(float* __restrict__ p, const float* __restrict__ pprn,
                        const int* __restrict__ offs) {
  int gid = blockIdx.x * 256 + threadIdx.x;  // T_N*8 threads
  int t = gid >> 3, k = gid & 7;
  int s = offs[t], en = offs[t + 1];
  if (s >= en) return;
  float m1 = -INFINITY;
  for (int e = s; e < en; ++e) m1 = fmaxf(m1, p[(size_t)e * 8 + k]);
  float s1 = 0.f;
  for (int e = s; e < en; ++e) s1 += expf(p[(size_t)e * 8 + k] - m1);
  float inv1 = 1.f / s1;
  float m2 = -INFINITY;
  for (int e = s; e < en; ++e) {
    float v = 0.5f * expf(p[(size_t)e * 8 + k] - m1) * inv1 + 0.5f * pprn[e];
    m2 = fmaxf(m2, v);
  }
  float s2 = 0.f;
  for (int e = s; e < en; ++e) {
    float v = 0.5f * expf(p[(size_t)e * 8 + k] - m1) * inv1 + 0.5f * pprn[e];
    s2 += expf(v - m2);
  }
  float inv2 = 1.f / s2;
  for (int e = s; e < en; ++e) {
    float v = 0.5f * expf(p[(size_t)e * 8 + k] - m1) * inv1 + 0.5f * pprn[e];
    p[(size_t)e * 8 + k] = expf(v - m2) * inv2;
  }
}

// ---------- kernel 7: logits = relu(u) @ mlp_w + mlp_b; log_softmax. wave per target ----
__global__ __launch_bounds__(256) void final_mlp(
    const float* __restrict__ u, const float* __restrict__ mw,
    const float* __restrict__ mb, float* __restrict__ out) {
  int wid = threadIdx.x >> 6, lane = threadIdx.x & 63;
  int t = blockIdx.x * 4 + wid;
  const float* ur = u + (size_t)t * 512 + lane * 8;
  float4 u0 = *(const float4*)(ur);
  float4 u1 = *(const float4*)(ur + 4);
  float ru[8] = {fmaxf(u0.x, 0.f), fmaxf(u0.y, 0.f), fmaxf(u0.z, 0.f), fmaxf(u0.w, 0.f),
                 fmaxf(u1.x, 0.f), fmaxf(u1.y, 0.f), fmaxf(u1.z, 0.f), fmaxf(u1.w, 0.f)};
  const float* wp = mw + (size_t)(lane * 8) * NCLS;
  float mx = -INFINITY, se = 0.f, myl = 0.f;
  for (int c = 0; c < NCLS; ++c) {
    float s = 0.f;
#pragma unroll
    for (int j = 0; j < 8; ++j) s += ru[j] * wp[j * NCLS + c];
    s += __shfl_xor(s, 32);
    s += __shfl_xor(s, 16);
    s += __shfl_xor(s, 8);
    s += __shfl_xor(s, 4);
    s += __shfl_xor(s, 2);
    s += __shfl_xor(s, 1);
    float lg = s + mb[c];
    if (lane == c) myl = lg;
    float nm = fmaxf(mx, lg);
    se = se * expf(mx - nm) + expf(lg - nm);
    mx = nm;
  }
  float lse = mx + logf(se);
  if (lane < NCLS) out[(size_t)t * NCLS + lane] = myl - lse;
}

// ---------- launch ----------
extern "C" void kernel_launch(void* const* d_in, const int* in_sizes, int n_in,
                              void* d_out, int out_size, void* d_ws, size_t ws_size,
                              hipStream_t stream) {
  const float* x_nb  = (const float*)d_in[0];
  const float* ppr   = (const float*)d_in[1];
  const float* pca_w = (const float*)d_in[2];
  const float* pca_b = (const float*)d_in[3];
  const float* mlp_w = (const float*)d_in[4];
  const float* mlp_b = (const float*)d_in[5];
  const int* row_idx = (const int*)d_in[6];
  const int* col_idx = (const int*)d_in[7];
  float* out = (float*)d_out;

  char* ws = (char*)d_ws;
  // workspace layout (bytes)
  const size_t OFF_BT   = 0;                          // 512*512*2      = 524288
  const size_t OFF_XN   = 524288;                     // NB*512*2       = 102400000
  const size_t OFF_U    = OFF_XN + 102400000;         // T*512*4        = 33554432
  const size_t OFF_P    = OFF_U + 33554432;           // E*8*4          = 4194304
  const size_t OFF_PPRN = OFF_P + 4194304;            // E*4            = 524288
  const size_t OFF_OFFS = OFF_PPRN + 524288;          // (T+1)*4
  u16*   Bt   = (u16*)(ws + OFF_BT);
  u16*   xn   = (u16*)(ws + OFF_XN);
  float* u    = (float*)(ws + OFF_U);
  float* p    = (float*)(ws + OFF_P);
  float* pprn = (float*)(ws + OFF_PPRN);
  int*   offs = (int*)(ws + OFF_OFFS);

  conv_bt<<<1024, 256, 0, stream>>>(pca_w, Bt);
  build_offs<<<512, 256, 0, stream>>>(row_idx, offs);
  ppr_sm<<<64, 256, 0, stream>>>(ppr, offs, pprn);
  gemm_pca<<<dim3(4, 782), 256, 0, stream>>>(x_nb, Bt, pca_b, xn);
  scatter_u<<<4096, 256, 0, stream>>>(xn, col_idx, offs, pprn, 1, 0, u);
  for (int it = 0; it < 3; ++it) {
    edge_logits<<<32768, 256, 0, stream>>>(xn, u, row_idx, col_idx, p);
    seg_sm2<<<512, 256, 0, stream>>>(p, pprn, offs);
    scatter_u<<<4096, 256, 0, stream>>>(xn, col_idx, offs, p, 0, (it < 2) ? 1 : 0, u);
  }
  final_mlp<<<4096, 256, 0, stream>>>(u, mlp_w, mlp_b, out);
}

// Round 2
// 887.417 us; speedup vs baseline: 1.7442x; 1.7442x over previous
//
#include <hip/hip_runtime.h>
#include <cstdint>
#include <cstddef>

// Problem constants (fixed by reference file)
#define NB_N 100000
#define E_N  131072
#define T_N  16384
#define D_N  512
#define NCLS 40

typedef unsigned short u16;
typedef unsigned int   u32;
typedef __attribute__((ext_vector_type(8))) short  short8;   // 8 bf16 (4 VGPRs)
typedef __attribute__((ext_vector_type(4))) float  floatx4;  // MFMA accumulator

// ---------- bf16 helpers (manual, RNE) ----------
__device__ __forceinline__ u16 f2bf(float f) {
  u32 u = __float_as_uint(f);
  return (u16)((u + 0x7fffu + ((u >> 16) & 1u)) >> 16);
}
__device__ __forceinline__ void unpack8(uint4 z, float* f) {
  f[0] = __uint_as_float(z.x << 16);
  f[1] = __uint_as_float(z.x & 0xffff0000u);
  f[2] = __uint_as_float(z.y << 16);
  f[3] = __uint_as_float(z.y & 0xffff0000u);
  f[4] = __uint_as_float(z.z << 16);
  f[5] = __uint_as_float(z.z & 0xffff0000u);
  f[6] = __uint_as_float(z.w << 16);
  f[7] = __uint_as_float(z.w & 0xffff0000u);
}
__device__ __forceinline__ void gload_lds16(const void* g, void* s) {
  __builtin_amdgcn_global_load_lds(
      (const __attribute__((address_space(1))) unsigned int*)g,
      (__attribute__((address_space(3))) unsigned int*)s, 16, 0, 0);
}

// ---------- kernel 0: transpose+convert pca_w (K,N) f32 -> Bt (N,K) bf16 ----------
__global__ void conv_bt(const float* __restrict__ w, u16* __restrict__ Bt) {
  int i = blockIdx.x * 256 + threadIdx.x;       // i over 512*512, i = n*512+k
  int n = i >> 9, k = i & 511;
  Bt[i] = f2bf(w[k * 512 + n]);
}

// ---------- kernel 0b: transpose+convert mlp_w (512,40) f32 -> Bt2 (64,512) bf16, zero-pad ----
__global__ void conv_bt2(const float* __restrict__ w, u16* __restrict__ Bt2) {
  int i = blockIdx.x * 256 + threadIdx.x;       // 64*512 elements, i = n*512+k
  int n = i >> 9, k = i & 511;
  Bt2[i] = (n < NCLS) ? f2bf(w[k * NCLS + n]) : (u16)0;
}

// ---------- kernel 1: CSR offsets from sorted row_idx ----------
__global__ void build_offs(const int* __restrict__ rowi, int* __restrict__ offs) {
  int e = blockIdx.x * 256 + threadIdx.x;
  if (e >= E_N) return;
  int r  = rowi[e];
  int rp = (e == 0) ? -1 : rowi[e - 1];
  for (int t = rp + 1; t <= r; ++t) offs[t] = e;
  if (e == E_N - 1)
    for (int t = r + 1; t <= T_N; ++t) offs[t] = E_N;
}

// ---------- kernel 2: segment softmax of ppr ----------
__global__ void ppr_sm(const float* __restrict__ ppr, const int* __restrict__ offs,
                       float* __restrict__ pprn) {
  int t = blockIdx.x * 256 + threadIdx.x;       // T_N threads
  int s = offs[t], en = offs[t + 1];
  if (s >= en) return;
  float m = -INFINITY;
  for (int e = s; e < en; ++e) m = fmaxf(m, ppr[e]);
  float sum = 0.f;
  for (int e = s; e < en; ++e) sum += expf(ppr[e] - m);
  float inv = 1.f / sum;
  for (int e = s; e < en; ++e) pprn[e] = expf(ppr[e] - m) * inv;
}

// ---------- kernel 3: bf16 MFMA GEMM x = relu(x_nb @ pca_w + b), per-capsule l2norm,
//            writes xn bf16 (NB, 512). 128x128 tile, BK=64, 4 waves. ----------
__global__ __launch_bounds__(256) void gemm_pca(
    const float* __restrict__ A,    // x_nb (NB,512) f32
    const u16*   __restrict__ Bt,   // (512,512) bf16, n-major (pre-transposed)
    const float* __restrict__ bias, // (512,)
    u16*         __restrict__ xn) { // (NB,512) bf16, normalized
  __shared__ u16 As[128 * 64];      // 16 KB
  __shared__ u16 Bs[128 * 64];      // 16 KB
  const int tid  = threadIdx.x;
  const int wid  = tid >> 6, lane = tid & 63;
  const int quad = lane >> 4, l16 = lane & 15;
  const int m0 = blockIdx.y * 128;
  const int n0 = blockIdx.x * 128;
  const int wm = (wid >> 1) * 64;   // wave tile origin within block
  const int wn = (wid & 1) * 64;

  floatx4 acc[4][4];
#pragma unroll
  for (int i = 0; i < 4; ++i)
#pragma unroll
    for (int j = 0; j < 4; ++j) acc[i][j] = (floatx4){0.f, 0.f, 0.f, 0.f};

  for (int k0 = 0; k0 < 512; k0 += 64) {
    // stage A (128 rows x 64 k) f32 -> bf16 in LDS, zero-pad rows >= NB
#pragma unroll
    for (int j = 0; j < 8; ++j) {
      int ci  = j * 256 + tid;      // 2048 float4 chunks
      int row = ci >> 4, c4 = ci & 15;
      int gm  = m0 + row;
      float4 va;
      if (gm < NB_N) va = *(const float4*)(A + (size_t)gm * 512 + k0 + (c4 << 2));
      else           va = make_float4(0.f, 0.f, 0.f, 0.f);
      uint2 pk;
      pk.x = (u32)f2bf(va.x) | ((u32)f2bf(va.y) << 16);
      pk.y = (u32)f2bf(va.z) | ((u32)f2bf(va.w) << 16);
      *(uint2*)(&As[(row << 6) + (c4 << 2)]) = pk;
    }
    // stage B via async global->LDS (16B/lane, wave-uniform LDS base + lane*16)
#pragma unroll
    for (int j = 0; j < 4; ++j) {
      int ci  = j * 256 + wid * 64 + lane;  // 16B chunk id, 1024 total
      int row = ci >> 3, kc = ci & 7;
      const void* g = (const void*)(Bt + (size_t)(n0 + row) * 512 + k0 + kc * 8);
      void* s = (void*)(&Bs[(size_t)(j * 256 + wid * 64) * 8]);
      gload_lds16(g, s);
    }
    __syncthreads();
#pragma unroll
    for (int kk = 0; kk < 64; kk += 32) {
      short8 af[4], bf[4];
#pragma unroll
      for (int mi = 0; mi < 4; ++mi)
        af[mi] = *(const short8*)(&As[(wm + mi * 16 + l16) * 64 + kk + quad * 8]);
#pragma unroll
      for (int ni = 0; ni < 4; ++ni)
        bf[ni] = *(const short8*)(&Bs[(wn + ni * 16 + l16) * 64 + kk + quad * 8]);
#pragma unroll
      for (int mi = 0; mi < 4; ++mi)
#pragma unroll
        for (int ni = 0; ni < 4; ++ni)
          acc[mi][ni] = __builtin_amdgcn_mfma_f32_16x16x32_bf16(af[mi], bf[ni],
                                                                acc[mi][ni], 0, 0, 0);
    }
    __syncthreads();
  }

  // epilogue: +bias, relu, per-capsule (64-col) l2norm, store bf16.
#pragma unroll
  for (int mi = 0; mi < 4; ++mi) {
#pragma unroll
    for (int r = 0; r < 4; ++r) {
      int gm = m0 + wm + mi * 16 + quad * 4 + r;
      float v[4];
      float ss = 0.f;
#pragma unroll
      for (int ni = 0; ni < 4; ++ni) {
        int n  = n0 + wn + ni * 16 + l16;
        float x = acc[mi][ni][r] + bias[n];
        x = fmaxf(x, 0.f);
        v[ni] = x;
        ss += x * x;
      }
      ss += __shfl_xor(ss, 1);
      ss += __shfl_xor(ss, 2);
      ss += __shfl_xor(ss, 4);
      ss += __shfl_xor(ss, 8);
      float sc = 1.f / fmaxf(sqrtf(ss), 1e-12f);
      if (gm < NB_N) {
#pragma unroll
        for (int ni = 0; ni < 4; ++ni) {
          int n = n0 + wn + ni * 16 + l16;
          xn[(size_t)gm * 512 + n] = f2bf(v[ni] * sc);
        }
      }
    }
  }
}

// ---------- kernel 4: u[t] = sum_e w_e * z_e (wave per target).
//            do_norm: per-capsule l2norm (intermediate rounds).
//            out_bf16: write ub = bf16(relu(u)) for the final MLP GEMM. ----------
__global__ __launch_bounds__(256) void scatter_u(
    const u16* __restrict__ xn, const int* __restrict__ coli,
    const int* __restrict__ offs, const float* __restrict__ we,
    int init, int do_norm, int out_bf16,
    float* __restrict__ u, u16* __restrict__ ub) {
  int wid = threadIdx.x >> 6, lane = threadIdx.x & 63;
  int t = blockIdx.x * 4 + wid;
  int s = offs[t], en = offs[t + 1];
  int cap = lane >> 3;                   // capsule of this lane's 8 dims
  float acc[8] = {0.f, 0.f, 0.f, 0.f, 0.f, 0.f, 0.f, 0.f};
  for (int e = s; e < en; ++e) {
    float w = init ? we[e] : we[(size_t)e * 8 + cap];
    uint4 zz = *(const uint4*)(xn + (size_t)coli[e] * 512 + lane * 8);
    float zf[8];
    unpack8(zz, zf);
#pragma unroll
    for (int j = 0; j < 8; ++j) acc[j] += w * zf[j];
  }
  if (do_norm) {
    float ss = 0.f;
#pragma unroll
    for (int j = 0; j < 8; ++j) ss += acc[j] * acc[j];
    ss += __shfl_xor(ss, 1);
    ss += __shfl_xor(ss, 2);
    ss += __shfl_xor(ss, 4);
    float sc = 1.f / fmaxf(sqrtf(ss), 1e-12f);
#pragma unroll
    for (int j = 0; j < 8; ++j) acc[j] *= sc;
  }
  if (out_bf16) {
    uint4 pk;
    pk.x = (u32)f2bf(fmaxf(acc[0], 0.f)) | ((u32)f2bf(fmaxf(acc[1], 0.f)) << 16);
    pk.y = (u32)f2bf(fmaxf(acc[2], 0.f)) | ((u32)f2bf(fmaxf(acc[3], 0.f)) << 16);
    pk.z = (u32)f2bf(fmaxf(acc[4], 0.f)) | ((u32)f2bf(fmaxf(acc[5], 0.f)) << 16);
    pk.w = (u32)f2bf(fmaxf(acc[6], 0.f)) | ((u32)f2bf(fmaxf(acc[7], 0.f)) << 16);
    *(uint4*)(ub + (size_t)t * 512 + lane * 8) = pk;
  } else {
    float* ur = u + (size_t)t * 512 + lane * 8;
    *(float4*)(ur)     = make_float4(acc[0], acc[1], acc[2], acc[3]);
    *(float4*)(ur + 4) = make_float4(acc[4], acc[5], acc[6], acc[7]);
  }
}

// ---------- kernel 5: per-edge capsule logits p[e][k] = <u[row_e]_k, z_e_k> ----------
__global__ __launch_bounds__(256) void edge_logits(
    const u16* __restrict__ xn, const float* __restrict__ u,
    const int* __restrict__ rowi, const int* __restrict__ coli,
    float* __restrict__ p) {
  int wid = threadIdx.x >> 6, lane = threadIdx.x & 63;
  int e = blockIdx.x * 4 + wid;
  int r = rowi[e], c = coli[e];
  uint4 zz = *(const uint4*)(xn + (size_t)c * 512 + lane * 8);
  float zf[8];
  unpack8(zz, zf);
  const float* ur = u + (size_t)r * 512 + lane * 8;
  float4 u0 = *(const float4*)(ur);
  float4 u1 = *(const float4*)(ur + 4);
  float s = u0.x * zf[0] + u0.y * zf[1] + u0.z * zf[2] + u0.w * zf[3] +
            u1.x * zf[4] + u1.y * zf[5] + u1.z * zf[6] + u1.w * zf[7];
  s += __shfl_xor(s, 1);
  s += __shfl_xor(s, 2);
  s += __shfl_xor(s, 4);
  if ((lane & 7) == 0) p[(size_t)e * 8 + (lane >> 3)] = s;
}

// ---------- kernel 6: p = segsm(p); p = 0.5*p + 0.5*pprn; p = segsm(p). thread per (t,k) ----
__global__ void seg_sm2(float* __restrict__ p, const float* __restrict__ pprn,
                        const int* __restrict__ offs) {
  int gid = blockIdx.x * 256 + threadIdx.x;  // T_N*8 threads
  int t = gid >> 3, k = gid & 7;
  int s = offs[t], en = offs[t + 1];
  if (s >= en) return;
  float m1 = -INFINITY;
  for (int e = s; e < en; ++e) m1 = fmaxf(m1, p[(size_t)e * 8 + k]);
  float s1 = 0.f;
  for (int e = s; e < en; ++e) s1 += expf(p[(size_t)e * 8 + k] - m1);
  float inv1 = 1.f / s1;
  float m2 = -INFINITY;
  for (int e = s; e < en; ++e) {
    float v = 0.5f * expf(p[(size_t)e * 8 + k] - m1) * inv1 + 0.5f * pprn[e];
    m2 = fmaxf(m2, v);
  }
  float s2 = 0.f;
  for (int e = s; e < en; ++e) {
    float v = 0.5f * expf(p[(size_t)e * 8 + k] - m1) * inv1 + 0.5f * pprn[e];
    s2 += expf(v - m2);
  }
  float inv2 = 1.f / s2;
  for (int e = s; e < en; ++e) {
    float v = 0.5f * expf(p[(size_t)e * 8 + k] - m1) * inv1 + 0.5f * pprn[e];
    p[(size_t)e * 8 + k] = expf(v - m2) * inv2;
  }
}

// ---------- kernel 7: logits = ub @ Bt2^T + mb; fused log_softmax epilogue.
//            ub (T,512) bf16 = relu(u); Bt2 (64,512) bf16 (rows 40..63 zero).
//            one wave per 16 targets; MFMA 16x16x32; N=64 in 4 ni-tiles.
//            C/D: col=l16 (class c=ni*16+l16), row=quad*4+r (target).
//            log_softmax reduces across l16 within each quad (shfl_xor 1,2,4,8). ----
__global__ __launch_bounds__(256) void mlp_gemm(
    const u16* __restrict__ ub, const u16* __restrict__ Bt2,
    const float* __restrict__ mb, float* __restrict__ out) {
  const int wid = threadIdx.x >> 6, lane = threadIdx.x & 63;
  const int quad = lane >> 4, l16 = lane & 15;
  const int m0 = blockIdx.x * 64 + wid * 16;

  floatx4 acc[4];
#pragma unroll
  for (int ni = 0; ni < 4; ++ni) acc[ni] = (floatx4){0.f, 0.f, 0.f, 0.f};

#pragma unroll 4
  for (int kk = 0; kk < 512; kk += 32) {
    short8 af = *(const short8*)(ub + (size_t)(m0 + l16) * 512 + kk + quad * 8);
#pragma unroll
    for (int ni = 0; ni < 4; ++ni) {
      short8 bf = *(const short8*)(Bt2 + (size_t)(ni * 16 + l16) * 512 + kk + quad * 8);
      acc[ni] = __builtin_amdgcn_mfma_f32_16x16x32_bf16(af, bf, acc[ni], 0, 0, 0);
    }
  }

  // epilogue: per target row, log_softmax over the 40 valid classes.
#pragma unroll
  for (int r = 0; r < 4; ++r) {
    int t = m0 + quad * 4 + r;
    float v[4];
    float mx = -INFINITY;
#pragma unroll
    for (int ni = 0; ni < 4; ++ni) {
      int c = ni * 16 + l16;
      bool valid = (c < NCLS);
      float lg = valid ? (acc[ni][r] + mb[c]) : -INFINITY;
      v[ni] = lg;
      mx = fmaxf(mx, lg);
    }
    mx = fmaxf(mx, __shfl_xor(mx, 1));
    mx = fmaxf(mx, __shfl_xor(mx, 2));
    mx = fmaxf(mx, __shfl_xor(mx, 4));
    mx = fmaxf(mx, __shfl_xor(mx, 8));
    float se = 0.f;
#pragma unroll
    for (int ni = 0; ni < 4; ++ni) {
      int c = ni * 16 + l16;
      if (c < NCLS) se += expf(v[ni] - mx);
    }
    se += __shfl_xor(se, 1);
    se += __shfl_xor(se, 2);
    se += __shfl_xor(se, 4);
    se += __shfl_xor(se, 8);
    float lse = mx + logf(se);
#pragma unroll
    for (int ni = 0; ni < 4; ++ni) {
      int c = ni * 16 + l16;
      if (c < NCLS) out[(size_t)t * NCLS + c] = v[ni] - lse;
    }
  }
}

// ---------- launch ----------
extern "C" void kernel_launch(void* const* d_in, const int* in_sizes, int n_in,
                              void* d_out, int out_size, void* d_ws, size_t ws_size,
                              hipStream_t stream) {
  const float* x_nb  = (const float*)d_in[0];
  const float* ppr   = (const float*)d_in[1];
  const float* pca_w = (const float*)d_in[2];
  const float* pca_b = (const float*)d_in[3];
  const float* mlp_w = (const float*)d_in[4];
  const float* mlp_b = (const float*)d_in[5];
  const int* row_idx = (const int*)d_in[6];
  const int* col_idx = (const int*)d_in[7];
  float* out = (float*)d_out;

  char* ws = (char*)d_ws;
  // workspace layout (bytes)
  const size_t OFF_BT   = 0;                          // 512*512*2      = 524288
  const size_t OFF_XN   = 524288;                     // NB*512*2       = 102400000
  const size_t OFF_U    = OFF_XN + 102400000;         // T*512*4        = 33554432
  const size_t OFF_P    = OFF_U + 33554432;           // E*8*4          = 4194304
  const size_t OFF_PPRN = OFF_P + 4194304;            // E*4            = 524288
  const size_t OFF_OFFS = OFF_PPRN + 524288;          // (T+1)*4
  u16*   Bt   = (u16*)(ws + OFF_BT);
  u16*   Bt2  = (u16*)(ws + OFF_BT);   // reuses Bt region after gemm_pca is done
  u16*   xn   = (u16*)(ws + OFF_XN);
  float* u    = (float*)(ws + OFF_U);
  u16*   ub   = (u16*)(ws + OFF_U);    // bf16 relu(u) aliases u region (final round)
  float* p    = (float*)(ws + OFF_P);
  float* pprn = (float*)(ws + OFF_PPRN);
  int*   offs = (int*)(ws + OFF_OFFS);

  conv_bt<<<1024, 256, 0, stream>>>(pca_w, Bt);
  build_offs<<<512, 256, 0, stream>>>(row_idx, offs);
  ppr_sm<<<64, 256, 0, stream>>>(ppr, offs, pprn);
  gemm_pca<<<dim3(4, 782), 256, 0, stream>>>(x_nb, Bt, pca_b, xn);
  conv_bt2<<<128, 256, 0, stream>>>(mlp_w, Bt2);   // after gemm_pca (region reuse)
  scatter_u<<<4096, 256, 0, stream>>>(xn, col_idx, offs, pprn, 1, 0, 0, u, ub);
  for (int it = 0; it < 3; ++it) {
    edge_logits<<<32768, 256, 0, stream>>>(xn, u, row_idx, col_idx, p);
    seg_sm2<<<512, 256, 0, stream>>>(p, pprn, offs);
    scatter_u<<<4096, 256, 0, stream>>>(xn, col_idx, offs, p, 0,
                                        (it < 2) ? 1 : 0, (it == 2) ? 1 : 0, u, ub);
  }
  mlp_gemm<<<256, 256, 0, stream>>>(ub, Bt2, mlp_b, out);
}

// Round 3
// 657.189 us; speedup vs baseline: 2.3552x; 1.3503x over previous
//
#include <hip/hip_runtime.h>
#include <cstdint>
#include <cstddef>

// Problem constants (fixed by reference file)
#define NB_N 100000
#define E_N  131072
#define T_N  16384
#define D_N  512
#define NCLS 40
#define NTILES 782          // ceil(100000/128); 782*128 = 100096

typedef unsigned short u16;
typedef unsigned int   u32;
typedef __attribute__((ext_vector_type(8))) short  short8;   // 8 bf16 (4 VGPRs)
typedef __attribute__((ext_vector_type(4))) float  floatx4;  // MFMA accumulator

// ---------- bf16 helpers (manual, RNE) ----------
__device__ __forceinline__ u16 f2bf(float f) {
  u32 u = __float_as_uint(f);
  return (u16)((u + 0x7fffu + ((u >> 16) & 1u)) >> 16);
}
__device__ __forceinline__ void unpack8(uint4 z, float* f) {
  f[0] = __uint_as_float(z.x << 16);
  f[1] = __uint_as_float(z.x & 0xffff0000u);
  f[2] = __uint_as_float(z.y << 16);
  f[3] = __uint_as_float(z.y & 0xffff0000u);
  f[4] = __uint_as_float(z.z << 16);
  f[5] = __uint_as_float(z.z & 0xffff0000u);
  f[6] = __uint_as_float(z.w << 16);
  f[7] = __uint_as_float(z.w & 0xffff0000u);
}
__device__ __forceinline__ void gload_lds16(const void* g, void* s) {
  __builtin_amdgcn_global_load_lds(
      (const __attribute__((address_space(1))) unsigned int*)g,
      (__attribute__((address_space(3))) unsigned int*)s, 16, 0, 0);
}

// ---------- kernel 0: transpose+convert pca_w (K,N) f32 -> Bt (N,K) bf16 ----------
__global__ void conv_bt(const float* __restrict__ w, u16* __restrict__ Bt) {
  int i = blockIdx.x * 256 + threadIdx.x;       // i over 512*512, i = n*512+k
  int n = i >> 9, k = i & 511;
  Bt[i] = f2bf(w[k * 512 + n]);
}

// ---------- kernel 0b: transpose+convert mlp_w (512,40) f32 -> Bt2 (64,512) bf16, zero-pad ----
__global__ void conv_bt2(const float* __restrict__ w, u16* __restrict__ Bt2) {
  int i = blockIdx.x * 256 + threadIdx.x;       // 64*512 elements, i = n*512+k
  int n = i >> 9, k = i & 511;
  Bt2[i] = (n < NCLS) ? f2bf(w[k * NCLS + n]) : (u16)0;
}

// ---------- kernel 0c: convert a chunk of x_nb f32 -> Ab bf16 (zero-pad rows >= NB) ----
__global__ void conv_a(const float* __restrict__ A, u16* __restrict__ Ab,
                       int r0, int rows) {
  int i = blockIdx.x * 256 + threadIdx.x;       // float4 id within chunk
  if (i >= rows * 128) return;                  // 128 float4 per 512-wide row
  int row = i >> 7;
  int grow = r0 + row;
  float4 v;
  if (grow < NB_N) v = ((const float4*)(A + (size_t)grow * 512))[i & 127];
  else             v = make_float4(0.f, 0.f, 0.f, 0.f);
  uint2 pk;
  pk.x = (u32)f2bf(v.x) | ((u32)f2bf(v.y) << 16);
  pk.y = (u32)f2bf(v.z) | ((u32)f2bf(v.w) << 16);
  *(uint2*)(Ab + (size_t)i * 4) = pk;
}

// ---------- kernel 1: CSR offsets from sorted row_idx ----------
__global__ void build_offs(const int* __restrict__ rowi, int* __restrict__ offs) {
  int e = blockIdx.x * 256 + threadIdx.x;
  if (e >= E_N) return;
  int r  = rowi[e];
  int rp = (e == 0) ? -1 : rowi[e - 1];
  for (int t = rp + 1; t <= r; ++t) offs[t] = e;
  if (e == E_N - 1)
    for (int t = r + 1; t <= T_N; ++t) offs[t] = E_N;
}

// ---------- kernel 2: segment softmax of ppr ----------
__global__ void ppr_sm(const float* __restrict__ ppr, const int* __restrict__ offs,
                       float* __restrict__ pprn) {
  int t = blockIdx.x * 256 + threadIdx.x;       // T_N threads
  int s = offs[t], en = offs[t + 1];
  if (s >= en) return;
  float m = -INFINITY;
  for (int e = s; e < en; ++e) m = fmaxf(m, ppr[e]);
  float sum = 0.f;
  for (int e = s; e < en; ++e) sum += expf(ppr[e] - m);
  float inv = 1.f / sum;
  for (int e = s; e < en; ++e) pprn[e] = expf(ppr[e] - m) * inv;
}

// ---------- kernel 3: bf16 MFMA GEMM x = relu(Ab @ pca_w + b), per-capsule l2norm,
//            writes xn bf16. 128x128 tile, BK=64, 4 waves. Both operands staged
//            via async global_load_lds (16B/lane) — no VGPR round-trip, no cvt. ----
__global__ __launch_bounds__(256) void gemm_pca(
    const u16*   __restrict__ Ab,   // chunk of x_nb, bf16 (rows r0..)
    const u16*   __restrict__ Bt,   // (512,512) bf16, n-major (pre-transposed)
    const float* __restrict__ bias, // (512,)
    u16*         __restrict__ xn,   // (NB,512) bf16, normalized
    int tile0, int r0) {
  __shared__ u16 As[128 * 64];      // 16 KB
  __shared__ u16 Bs[128 * 64];      // 16 KB
  const int tid  = threadIdx.x;
  const int wid  = tid >> 6, lane = tid & 63;
  const int quad = lane >> 4, l16 = lane & 15;
  const int m0 = (tile0 + blockIdx.y) * 128;
  const int n0 = blockIdx.x * 128;
  const int wm = (wid >> 1) * 64;
  const int wn = (wid & 1) * 64;
  const u16* Arow = Ab + (size_t)(m0 - r0) * 512;

  floatx4 acc[4][4];
#pragma unroll
  for (int i = 0; i < 4; ++i)
#pragma unroll
    for (int j = 0; j < 4; ++j) acc[i][j] = (floatx4){0.f, 0.f, 0.f, 0.f};

  for (int k0 = 0; k0 < 512; k0 += 64) {
    // stage A and B tiles: 1024 16B-chunks each, 4 per thread, all async DMA
#pragma unroll
    for (int j = 0; j < 4; ++j) {
      int ci  = j * 256 + wid * 64 + lane;  // chunk id (wave-contiguous)
      int row = ci >> 3, kc = ci & 7;       // 8 chunks per 64-elem row
      gload_lds16(Arow + (size_t)row * 512 + k0 + kc * 8,
                  &As[(size_t)(j * 256 + wid * 64) * 8]);
      gload_lds16(Bt + (size_t)(n0 + row) * 512 + k0 + kc * 8,
                  &Bs[(size_t)(j * 256 + wid * 64) * 8]);
    }
    __syncthreads();
#pragma unroll
    for (int kk = 0; kk < 64; kk += 32) {
      short8 af[4], bf[4];
#pragma unroll
      for (int mi = 0; mi < 4; ++mi)
        af[mi] = *(const short8*)(&As[(wm + mi * 16 + l16) * 64 + kk + quad * 8]);
#pragma unroll
      for (int ni = 0; ni < 4; ++ni)
        bf[ni] = *(const short8*)(&Bs[(wn + ni * 16 + l16) * 64 + kk + quad * 8]);
#pragma unroll
      for (int mi = 0; mi < 4; ++mi)
#pragma unroll
        for (int ni = 0; ni < 4; ++ni)
          acc[mi][ni] = __builtin_amdgcn_mfma_f32_16x16x32_bf16(af[mi], bf[ni],
                                                                acc[mi][ni], 0, 0, 0);
    }
    __syncthreads();
  }

  // epilogue: +bias, relu, per-capsule (64-col) l2norm, store bf16.
#pragma unroll
  for (int mi = 0; mi < 4; ++mi) {
#pragma unroll
    for (int r = 0; r < 4; ++r) {
      int gm = m0 + wm + mi * 16 + quad * 4 + r;
      float v[4];
      float ss = 0.f;
#pragma unroll
      for (int ni = 0; ni < 4; ++ni) {
        int n  = n0 + wn + ni * 16 + l16;
        float x = acc[mi][ni][r] + bias[n];
        x = fmaxf(x, 0.f);
        v[ni] = x;
        ss += x * x;
      }
      ss += __shfl_xor(ss, 1);
      ss += __shfl_xor(ss, 2);
      ss += __shfl_xor(ss, 4);
      ss += __shfl_xor(ss, 8);
      float sc = 1.f / fmaxf(sqrtf(ss), 1e-12f);
      if (gm < NB_N) {
#pragma unroll
        for (int ni = 0; ni < 4; ++ni) {
          int n = n0 + wn + ni * 16 + l16;
          xn[(size_t)gm * 512 + n] = f2bf(v[ni] * sc);
        }
      }
    }
  }
}

// ---------- kernel 4: one full routing round, wave per target.
//            init: build u0 = sum pprn*z in-regs instead of reading u.
//            phase1: capsule logits -> LDS; phase2: double segment-softmax in LDS;
//            phase3: u_new = sum w*z (+optional per-capsule l2norm), store f32. ----
__global__ __launch_bounds__(256) void fused_round(
    const u16* __restrict__ xn, const int* __restrict__ coli,
    const int* __restrict__ offs, const float* __restrict__ pprn,
    float* __restrict__ u, int init, int do_norm) {
  __shared__ float P[4][64 * 8];    // 8 KB: per-wave [edge][capsule] scratch
  const int wid = threadIdx.x >> 6, lane = threadIdx.x & 63;
  const int t = blockIdx.x * 4 + wid;
  float* Pw = P[wid];
  const int s = offs[t], en = offs[t + 1];
  int deg = en - s;
  if (deg > 64) deg = 64;           // Poisson(8): P(deg>64) ~ 1e-40, memory guard

  // u_t into registers (8 dims per lane; capsule = lane>>3)
  float uf[8];
  if (init) {
#pragma unroll
    for (int q = 0; q < 8; ++q) uf[q] = 0.f;
    for (int j = 0; j < deg; ++j) {
      int e = s + j;
      float w = pprn[e];
      uint4 zz = *(const uint4*)(xn + (size_t)coli[e] * 512 + lane * 8);
      float zf[8];
      unpack8(zz, zf);
#pragma unroll
      for (int q = 0; q < 8; ++q) uf[q] += w * zf[q];
    }
  } else {
    const float* ur = u + (size_t)t * 512 + lane * 8;
    float4 a = *(const float4*)ur, b = *(const float4*)(ur + 4);
    uf[0] = a.x; uf[1] = a.y; uf[2] = a.z; uf[3] = a.w;
    uf[4] = b.x; uf[5] = b.y; uf[6] = b.z; uf[7] = b.w;
  }

  // phase 1: per-edge capsule logits
  for (int j = 0; j < deg; ++j) {
    int e = s + j;
    uint4 zz = *(const uint4*)(xn + (size_t)coli[e] * 512 + lane * 8);
    float zf[8];
    unpack8(zz, zf);
    float d = uf[0] * zf[0] + uf[1] * zf[1] + uf[2] * zf[2] + uf[3] * zf[3] +
              uf[4] * zf[4] + uf[5] * zf[5] + uf[6] * zf[6] + uf[7] * zf[7];
    d += __shfl_xor(d, 1);
    d += __shfl_xor(d, 2);
    d += __shfl_xor(d, 4);
    if ((lane & 7) == 0) Pw[j * 8 + (lane >> 3)] = d;
  }
  __syncthreads();

  // phase 2: segsm -> blend 0.5/0.5 with pprn -> segsm. lane owns (j%8==slot, cap).
  {
    const int cap = lane & 7, slot = lane >> 3;
    float m1 = -INFINITY;
    for (int j = slot; j < deg; j += 8) m1 = fmaxf(m1, Pw[j * 8 + cap]);
    m1 = fmaxf(m1, __shfl_xor(m1, 8));
    m1 = fmaxf(m1, __shfl_xor(m1, 16));
    m1 = fmaxf(m1, __shfl_xor(m1, 32));
    float s1 = 0.f;
    for (int j = slot; j < deg; j += 8) s1 += expf(Pw[j * 8 + cap] - m1);
    s1 += __shfl_xor(s1, 8);
    s1 += __shfl_xor(s1, 16);
    s1 += __shfl_xor(s1, 32);
    float inv1 = 1.f / s1;
    float m2 = -INFINITY;
    for (int j = slot; j < deg; j += 8) {
      float v = 0.5f * expf(Pw[j * 8 + cap] - m1) * inv1 + 0.5f * pprn[s + j];
      Pw[j * 8 + cap] = v;     // each (j,cap) owned by exactly one lane
      m2 = fmaxf(m2, v);
    }
    m2 = fmaxf(m2, __shfl_xor(m2, 8));
    m2 = fmaxf(m2, __shfl_xor(m2, 16));
    m2 = fmaxf(m2, __shfl_xor(m2, 32));
    float s2 = 0.f;
    for (int j = slot; j < deg; j += 8) s2 += expf(Pw[j * 8 + cap] - m2);
    s2 += __shfl_xor(s2, 8);
    s2 += __shfl_xor(s2, 16);
    s2 += __shfl_xor(s2, 32);
    float inv2 = 1.f / s2;
    for (int j = slot; j < deg; j += 8)
      Pw[j * 8 + cap] = expf(Pw[j * 8 + cap] - m2) * inv2;
  }
  __syncthreads();

  // phase 3: weighted scatter-sum (z re-gather is L1/L2-warm from phase 1)
  float acc[8] = {0.f, 0.f, 0.f, 0.f, 0.f, 0.f, 0.f, 0.f};
  for (int j = 0; j < deg; ++j) {
    int e = s + j;
    float w = Pw[j * 8 + (lane >> 3)];
    uint4 zz = *(const uint4*)(xn + (size_t)coli[e] * 512 + lane * 8);
    float zf[8];
    unpack8(zz, zf);
#pragma unroll
    for (int q = 0; q < 8; ++q) acc[q] += w * zf[q];
  }
  if (do_norm) {
    float ss = 0.f;
#pragma unroll
    for (int q = 0; q < 8; ++q) ss += acc[q] * acc[q];
    ss += __shfl_xor(ss, 1);
    ss += __shfl_xor(ss, 2);
    ss += __shfl_xor(ss, 4);
    float sc = 1.f / fmaxf(sqrtf(ss), 1e-12f);
#pragma unroll
    for (int q = 0; q < 8; ++q) acc[q] *= sc;
  }
  float* uo = u + (size_t)t * 512 + lane * 8;
  *(float4*)(uo)     = make_float4(acc[0], acc[1], acc[2], acc[3]);
  *(float4*)(uo + 4) = make_float4(acc[4], acc[5], acc[6], acc[7]);
}

// ---------- kernel 5: logits = relu(u) @ Bt2^T + mb; fused log_softmax.
//            u (T,512) f32; relu+cvt to bf16 fragments in-kernel. ----------
__global__ __launch_bounds__(256) void mlp_gemm(
    const float* __restrict__ u, const u16* __restrict__ Bt2,
    const float* __restrict__ mb, float* __restrict__ out) {
  const int wid = threadIdx.x >> 6, lane = threadIdx.x & 63;
  const int quad = lane >> 4, l16 = lane & 15;
  const int m0 = blockIdx.x * 64 + wid * 16;

  floatx4 acc[4];
#pragma unroll
  for (int ni = 0; ni < 4; ++ni) acc[ni] = (floatx4){0.f, 0.f, 0.f, 0.f};

#pragma unroll 4
  for (int kk = 0; kk < 512; kk += 32) {
    const float* ar = u + (size_t)(m0 + l16) * 512 + kk + quad * 8;
    float4 a0 = *(const float4*)ar;
    float4 a1 = *(const float4*)(ar + 4);
    short8 af;
    af[0] = (short)f2bf(fmaxf(a0.x, 0.f));
    af[1] = (short)f2bf(fmaxf(a0.y, 0.f));
    af[2] = (short)f2bf(fmaxf(a0.z, 0.f));
    af[3] = (short)f2bf(fmaxf(a0.w, 0.f));
    af[4] = (short)f2bf(fmaxf(a1.x, 0.f));
    af[5] = (short)f2bf(fmaxf(a1.y, 0.f));
    af[6] = (short)f2bf(fmaxf(a1.z, 0.f));
    af[7] = (short)f2bf(fmaxf(a1.w, 0.f));
#pragma unroll
    for (int ni = 0; ni < 4; ++ni) {
      short8 bf = *(const short8*)(Bt2 + (size_t)(ni * 16 + l16) * 512 + kk + quad * 8);
      acc[ni] = __builtin_amdgcn_mfma_f32_16x16x32_bf16(af, bf, acc[ni], 0, 0, 0);
    }
  }

#pragma unroll
  for (int r = 0; r < 4; ++r) {
    int t = m0 + quad * 4 + r;
    float v[4];
    float mx = -INFINITY;
#pragma unroll
    for (int ni = 0; ni < 4; ++ni) {
      int c = ni * 16 + l16;
      float lg = (c < NCLS) ? (acc[ni][r] + mb[c]) : -INFINITY;
      v[ni] = lg;
      mx = fmaxf(mx, lg);
    }
    mx = fmaxf(mx, __shfl_xor(mx, 1));
    mx = fmaxf(mx, __shfl_xor(mx, 2));
    mx = fmaxf(mx, __shfl_xor(mx, 4));
    mx = fmaxf(mx, __shfl_xor(mx, 8));
    float se = 0.f;
#pragma unroll
    for (int ni = 0; ni < 4; ++ni) {
      int c = ni * 16 + l16;
      if (c < NCLS) se += expf(v[ni] - mx);
    }
    se += __shfl_xor(se, 1);
    se += __shfl_xor(se, 2);
    se += __shfl_xor(se, 4);
    se += __shfl_xor(se, 8);
    float lse = mx + logf(se);
#pragma unroll
    for (int ni = 0; ni < 4; ++ni) {
      int c = ni * 16 + l16;
      if (c < NCLS) out[(size_t)t * NCLS + c] = v[ni] - lse;
    }
  }
}

// ---------- launch ----------
extern "C" void kernel_launch(void* const* d_in, const int* in_sizes, int n_in,
                              void* d_out, int out_size, void* d_ws, size_t ws_size,
                              hipStream_t stream) {
  const float* x_nb  = (const float*)d_in[0];
  const float* ppr   = (const float*)d_in[1];
  const float* pca_w = (const float*)d_in[2];
  const float* pca_b = (const float*)d_in[3];
  const float* mlp_w = (const float*)d_in[4];
  const float* mlp_b = (const float*)d_in[5];
  const int* row_idx = (const int*)d_in[6];
  const int* col_idx = (const int*)d_in[7];
  float* out = (float*)d_out;

  char* ws = (char*)d_ws;
  // workspace layout (bytes), peak ~137.2 MB:
  //   BT   [0, 512K)            Bt, later reused as Bt2
  //   PPRN [512K, 1M)           E*4
  //   OFFS [1M, 1M+128K)        (T+1)*4
  //   XN   [1.125M, +102.4M)    NB*512*2
  //   AB   [103.6M, +25.7M)     bf16 A chunk (196 tiles); dead after gemm loop
  //   U    [103.6M, +33.6M)     aliases AB (written only after gemm loop)
  const size_t OFF_BT   = 0;
  const size_t OFF_PPRN = 512 * 1024;
  const size_t OFF_OFFS = 1024 * 1024;
  const size_t OFF_XN   = 1024 * 1024 + 128 * 1024;
  const size_t OFF_AB   = OFF_XN + (size_t)NB_N * 512 * 2;   // 103,604,224
  const size_t OFF_U    = OFF_AB;                            // alias (disjoint lifetime)
  u16*   Bt   = (u16*)(ws + OFF_BT);
  u16*   Bt2  = (u16*)(ws + OFF_BT);
  float* pprn = (float*)(ws + OFF_PPRN);
  int*   offs = (int*)(ws + OFF_OFFS);
  u16*   xn   = (u16*)(ws + OFF_XN);
  u16*   Ab   = (u16*)(ws + OFF_AB);
  float* u    = (float*)(ws + OFF_U);

  conv_bt<<<1024, 256, 0, stream>>>(pca_w, Bt);
  build_offs<<<512, 256, 0, stream>>>(row_idx, offs);
  ppr_sm<<<64, 256, 0, stream>>>(ppr, offs, pprn);

  // chunked PCA GEMM: convert f32->bf16 per chunk, then all-DMA MFMA GEMM
  int tile0 = 0;
  for (int c = 0; c < 4; ++c) {
    int tiles = (c < 3) ? 196 : (NTILES - 588);   // 196,196,196,194
    int r0 = tile0 * 128;
    int rows = tiles * 128;
    int nf4 = rows * 128;
    conv_a<<<(nf4 + 255) / 256, 256, 0, stream>>>(x_nb, Ab, r0, rows);
    gemm_pca<<<dim3(4, tiles), 256, 0, stream>>>(Ab, Bt, pca_b, xn, tile0, r0);
    tile0 += tiles;
  }
  conv_bt2<<<128, 256, 0, stream>>>(mlp_w, Bt2);  // after gemm loop (Bt region reuse)

  // 3 fused routing rounds (round 0 builds u0 from pprn in-wave)
  fused_round<<<4096, 256, 0, stream>>>(xn, col_idx, offs, pprn, u, 1, 1);
  fused_round<<<4096, 256, 0, stream>>>(xn, col_idx, offs, pprn, u, 0, 1);
  fused_round<<<4096, 256, 0, stream>>>(xn, col_idx, offs, pprn, u, 0, 0);

  mlp_gemm<<<256, 256, 0, stream>>>(u, Bt2, mlp_b, out);
}

// Round 4
// 577.333 us; speedup vs baseline: 2.6809x; 1.1383x over previous
//
#include <hip/hip_runtime.h>
#include <cstdint>
#include <cstddef>

// Problem constants (fixed by reference file)
#define NB_N 100000
#define E_N  131072
#define T_N  16384
#define D_N  512
#define NCLS 40
#define NTILES 782          // ceil(100000/128); 782*128 = 100096
#define CAP 16              // LDS z-cache edges per target (P(deg>16|Poisson(8))~0.4%)

typedef unsigned short u16;
typedef unsigned int   u32;
typedef __attribute__((ext_vector_type(8))) short  short8;   // 8 bf16 (4 VGPRs)
typedef __attribute__((ext_vector_type(4))) float  floatx4;  // MFMA accumulator

// ---------- bf16 helpers (manual, RNE) ----------
__device__ __forceinline__ u16 f2bf(float f) {
  u32 u = __float_as_uint(f);
  return (u16)((u + 0x7fffu + ((u >> 16) & 1u)) >> 16);
}
__device__ __forceinline__ void unpack8(uint4 z, float* f) {
  f[0] = __uint_as_float(z.x << 16);
  f[1] = __uint_as_float(z.x & 0xffff0000u);
  f[2] = __uint_as_float(z.y << 16);
  f[3] = __uint_as_float(z.y & 0xffff0000u);
  f[4] = __uint_as_float(z.z << 16);
  f[5] = __uint_as_float(z.z & 0xffff0000u);
  f[6] = __uint_as_float(z.w << 16);
  f[7] = __uint_as_float(z.w & 0xffff0000u);
}
__device__ __forceinline__ void gload_lds16(const void* g, void* s) {
  __builtin_amdgcn_global_load_lds(
      (const __attribute__((address_space(1))) unsigned int*)g,
      (__attribute__((address_space(3))) unsigned int*)s, 16, 0, 0);
}

// ---------- kernel 0: transpose+convert pca_w (K,N) f32 -> Bt (N,K) bf16 ----------
__global__ void conv_bt(const float* __restrict__ w, u16* __restrict__ Bt) {
  int i = blockIdx.x * 256 + threadIdx.x;       // i over 512*512, i = n*512+k
  int n = i >> 9, k = i & 511;
  Bt[i] = f2bf(w[k * 512 + n]);
}

// ---------- kernel 0b: transpose+convert mlp_w (512,40) f32 -> Bt2 (64,512) bf16, zero-pad ----
__global__ void conv_bt2(const float* __restrict__ w, u16* __restrict__ Bt2) {
  int i = blockIdx.x * 256 + threadIdx.x;       // 64*512 elements, i = n*512+k
  int n = i >> 9, k = i & 511;
  Bt2[i] = (n < NCLS) ? f2bf(w[k * NCLS + n]) : (u16)0;
}

// ---------- kernel 0c: convert all of x_nb f32 -> Ab bf16 (zero-pad rows >= NB) ----
__global__ void conv_a(const float* __restrict__ A, u16* __restrict__ Ab) {
  int i = blockIdx.x * 256 + threadIdx.x;       // float4 id
  if (i >= NTILES * 128 * 128) return;          // 128 float4 per 512-wide row
  int row = i >> 7;
  float4 v;
  if (row < NB_N) v = ((const float4*)(A + (size_t)row * 512))[i & 127];
  else            v = make_float4(0.f, 0.f, 0.f, 0.f);
  uint2 pk;
  pk.x = (u32)f2bf(v.x) | ((u32)f2bf(v.y) << 16);
  pk.y = (u32)f2bf(v.z) | ((u32)f2bf(v.w) << 16);
  *(uint2*)(Ab + (size_t)i * 4) = pk;
}

// ---------- kernel 1: CSR offsets from sorted row_idx ----------
__global__ void build_offs(const int* __restrict__ rowi, int* __restrict__ offs) {
  int e = blockIdx.x * 256 + threadIdx.x;
  if (e >= E_N) return;
  int r  = rowi[e];
  int rp = (e == 0) ? -1 : rowi[e - 1];
  for (int t = rp + 1; t <= r; ++t) offs[t] = e;
  if (e == E_N - 1)
    for (int t = r + 1; t <= T_N; ++t) offs[t] = E_N;
}

// ---------- kernel 2: segment softmax of ppr ----------
__global__ void ppr_sm(const float* __restrict__ ppr, const int* __restrict__ offs,
                       float* __restrict__ pprn) {
  int t = blockIdx.x * 256 + threadIdx.x;       // T_N threads
  int s = offs[t], en = offs[t + 1];
  if (s >= en) return;
  float m = -INFINITY;
  for (int e = s; e < en; ++e) m = fmaxf(m, ppr[e]);
  float sum = 0.f;
  for (int e = s; e < en; ++e) sum += expf(ppr[e] - m);
  float inv = 1.f / sum;
  for (int e = s; e < en; ++e) pprn[e] = expf(ppr[e] - m) * inv;
}

// ---------- kernel 3: bf16 MFMA GEMM x = relu(Ab @ pca_w + b), per-capsule l2norm,
//            writes xn bf16. 128x128 tile, BK=64, 4 waves, all-DMA staging. ----------
__global__ __launch_bounds__(256) void gemm_pca(
    const u16*   __restrict__ Ab,   // (NTILES*128, 512) bf16
    const u16*   __restrict__ Bt,   // (512,512) bf16, n-major (pre-transposed)
    const float* __restrict__ bias, // (512,)
    u16*         __restrict__ xn) { // (NB,512) bf16, normalized
  __shared__ u16 As[128 * 64];      // 16 KB
  __shared__ u16 Bs[128 * 64];      // 16 KB
  const int tid  = threadIdx.x;
  const int wid  = tid >> 6, lane = tid & 63;
  const int quad = lane >> 4, l16 = lane & 15;
  const int m0 = blockIdx.y * 128;
  const int n0 = blockIdx.x * 128;
  const int wm = (wid >> 1) * 64;
  const int wn = (wid & 1) * 64;
  const u16* Arow = Ab + (size_t)m0 * 512;

  floatx4 acc[4][4];
#pragma unroll
  for (int i = 0; i < 4; ++i)
#pragma unroll
    for (int j = 0; j < 4; ++j) acc[i][j] = (floatx4){0.f, 0.f, 0.f, 0.f};

  for (int k0 = 0; k0 < 512; k0 += 64) {
#pragma unroll
    for (int j = 0; j < 4; ++j) {
      int ci  = j * 256 + wid * 64 + lane;  // chunk id (wave-contiguous)
      int row = ci >> 3, kc = ci & 7;       // 8 chunks per 64-elem row
      gload_lds16(Arow + (size_t)row * 512 + k0 + kc * 8,
                  &As[(size_t)(j * 256 + wid * 64) * 8]);
      gload_lds16(Bt + (size_t)(n0 + row) * 512 + k0 + kc * 8,
                  &Bs[(size_t)(j * 256 + wid * 64) * 8]);
    }
    __syncthreads();
#pragma unroll
    for (int kk = 0; kk < 64; kk += 32) {
      short8 af[4], bf[4];
#pragma unroll
      for (int mi = 0; mi < 4; ++mi)
        af[mi] = *(const short8*)(&As[(wm + mi * 16 + l16) * 64 + kk + quad * 8]);
#pragma unroll
      for (int ni = 0; ni < 4; ++ni)
        bf[ni] = *(const short8*)(&Bs[(wn + ni * 16 + l16) * 64 + kk + quad * 8]);
#pragma unroll
      for (int mi = 0; mi < 4; ++mi)
#pragma unroll
        for (int ni = 0; ni < 4; ++ni)
          acc[mi][ni] = __builtin_amdgcn_mfma_f32_16x16x32_bf16(af[mi], bf[ni],
                                                                acc[mi][ni], 0, 0, 0);
    }
    __syncthreads();
  }

  // epilogue: +bias, relu, per-capsule (64-col) l2norm, store bf16.
#pragma unroll
  for (int mi = 0; mi < 4; ++mi) {
#pragma unroll
    for (int r = 0; r < 4; ++r) {
      int gm = m0 + wm + mi * 16 + quad * 4 + r;
      float v[4];
      float ss = 0.f;
#pragma unroll
      for (int ni = 0; ni < 4; ++ni) {
        int n  = n0 + wn + ni * 16 + l16;
        float x = acc[mi][ni][r] + bias[n];
        x = fmaxf(x, 0.f);
        v[ni] = x;
        ss += x * x;
      }
      ss += __shfl_xor(ss, 1);
      ss += __shfl_xor(ss, 2);
      ss += __shfl_xor(ss, 4);
      ss += __shfl_xor(ss, 8);
      float sc = 1.f / fmaxf(sqrtf(ss), 1e-12f);
      if (gm < NB_N) {
#pragma unroll
        for (int ni = 0; ni < 4; ++ni) {
          int n = n0 + wn + ni * 16 + l16;
          xn[(size_t)gm * 512 + n] = f2bf(v[ni] * sc);
        }
      }
    }
  }
}

// ---------- kernel 4: ALL routing (init + 3 rounds) for one target per wave.
//            Routing is target-local: u[t] depends only on this target's edges.
//            Gather z once via DMA into LDS cache (CAP edges); tail re-fetches global.
//            Block = 1 wave (64 threads) -> __syncthreads is wave-cheap & safe. ----
__global__ __launch_bounds__(64) void fused_all(
    const u16* __restrict__ xn, const int* __restrict__ coli,
    const int* __restrict__ offs, const float* __restrict__ pprn,
    u16* __restrict__ ub) {
  __shared__ u16   zc[CAP * 512];   // 16 KB z-cache (bf16 rows)
  __shared__ float P[64 * 8];       // 2 KB per-edge capsule weights
  const int lane = threadIdx.x;
  const int t = blockIdx.x;
  const int s = offs[t], en = offs[t + 1];
  int deg = en - s;
  if (deg > 64) deg = 64;           // Poisson(8): max over 16k targets ~27
  const int ncache = (deg < CAP) ? deg : CAP;
  const int cap = lane >> 3;        // capsule owning this lane's 8 dims

  int   mycol = (lane < deg) ? coli[s + lane] : 0;
  float myppr = (lane < deg) ? pprn[s + lane] : 0.f;

  // one-shot DMA gather of the first CAP edges' z rows into LDS
  for (int j = 0; j < ncache; ++j) {
    int c = __shfl(mycol, j);       // uniform j -> safe
    gload_lds16(xn + (size_t)c * 512 + lane * 8, &zc[j * 512]);
  }
  __syncthreads();                  // drains DMA (vmcnt) + visibility

  // fetch edge j's 8 dims for this lane (LDS if cached, else global)
#define FETCH_Z(j, zf)                                                        \
  {                                                                           \
    uint4 zz;                                                                 \
    if ((j) < CAP) zz = *(const uint4*)(&zc[(j) * 512 + lane * 8]);           \
    else {                                                                    \
      int c_ = __shfl(mycol, (j));                                            \
      zz = *(const uint4*)(xn + (size_t)c_ * 512 + lane * 8);                 \
    }                                                                         \
    unpack8(zz, zf);                                                          \
  }

  // init: u0 = sum_e pprn_e * z_e
  float uf[8] = {0.f, 0.f, 0.f, 0.f, 0.f, 0.f, 0.f, 0.f};
  for (int j = 0; j < deg; ++j) {
    float w = __shfl(myppr, j);
    float zf[8];
    FETCH_Z(j, zf);
#pragma unroll
    for (int q = 0; q < 8; ++q) uf[q] += w * zf[q];
  }

  for (int it = 0; it < 3; ++it) {
    // phase 1: capsule logits p[j][cap] = <u_cap, z_j_cap>
    for (int j = 0; j < deg; ++j) {
      float zf[8];
      FETCH_Z(j, zf);
      float d = uf[0] * zf[0] + uf[1] * zf[1] + uf[2] * zf[2] + uf[3] * zf[3] +
                uf[4] * zf[4] + uf[5] * zf[5] + uf[6] * zf[6] + uf[7] * zf[7];
      d += __shfl_xor(d, 1);
      d += __shfl_xor(d, 2);
      d += __shfl_xor(d, 4);
      if ((lane & 7) == 0) P[j * 8 + cap] = d;
    }
    __syncthreads();

    // phase 2: segsm -> 0.5/0.5 blend with pprn -> segsm (lane owns slot=lane>>3, capsule=lane&7)
    {
      const int c2 = lane & 7, slot = lane >> 3;
      float m1 = -INFINITY;
      for (int j = slot; j < deg; j += 8) m1 = fmaxf(m1, P[j * 8 + c2]);
      m1 = fmaxf(m1, __shfl_xor(m1, 8));
      m1 = fmaxf(m1, __shfl_xor(m1, 16));
      m1 = fmaxf(m1, __shfl_xor(m1, 32));
      float s1 = 0.f;
      for (int j = slot; j < deg; j += 8) s1 += expf(P[j * 8 + c2] - m1);
      s1 += __shfl_xor(s1, 8);
      s1 += __shfl_xor(s1, 16);
      s1 += __shfl_xor(s1, 32);
      float inv1 = 1.f / s1;
      float m2 = -INFINITY;
      for (int j = slot; j < deg; j += 8) {
        float v = 0.5f * expf(P[j * 8 + c2] - m1) * inv1 + 0.5f * pprn[s + j];
        P[j * 8 + c2] = v;          // each (j,cap) owned by exactly one lane
        m2 = fmaxf(m2, v);
      }
      m2 = fmaxf(m2, __shfl_xor(m2, 8));
      m2 = fmaxf(m2, __shfl_xor(m2, 16));
      m2 = fmaxf(m2, __shfl_xor(m2, 32));
      float s2 = 0.f;
      for (int j = slot; j < deg; j += 8) s2 += expf(P[j * 8 + c2] - m2);
      s2 += __shfl_xor(s2, 8);
      s2 += __shfl_xor(s2, 16);
      s2 += __shfl_xor(s2, 32);
      float inv2 = 1.f / s2;
      for (int j = slot; j < deg; j += 8)
        P[j * 8 + c2] = expf(P[j * 8 + c2] - m2) * inv2;
    }
    __syncthreads();

    // phase 3: u_new = sum_e p[e][cap] * z_e (+capsule l2norm except last round)
    float acc[8] = {0.f, 0.f, 0.f, 0.f, 0.f, 0.f, 0.f, 0.f};
    for (int j = 0; j < deg; ++j) {
      float w = P[j * 8 + cap];
      float zf[8];
      FETCH_Z(j, zf);
#pragma unroll
      for (int q = 0; q < 8; ++q) acc[q] += w * zf[q];
    }
    if (it < 2) {
      float ss = 0.f;
#pragma unroll
      for (int q = 0; q < 8; ++q) ss += acc[q] * acc[q];
      ss += __shfl_xor(ss, 1);
      ss += __shfl_xor(ss, 2);
      ss += __shfl_xor(ss, 4);
      float sc = 1.f / fmaxf(sqrtf(ss), 1e-12f);
#pragma unroll
      for (int q = 0; q < 8; ++q) acc[q] *= sc;
    }
#pragma unroll
    for (int q = 0; q < 8; ++q) uf[q] = acc[q];
    __syncthreads();                // P reads done before next round's writes
  }

  // output: ub = bf16(relu(u)) for the MLP GEMM
  uint4 pk;
  pk.x = (u32)f2bf(fmaxf(uf[0], 0.f)) | ((u32)f2bf(fmaxf(uf[1], 0.f)) << 16);
  pk.y = (u32)f2bf(fmaxf(uf[2], 0.f)) | ((u32)f2bf(fmaxf(uf[3], 0.f)) << 16);
  pk.z = (u32)f2bf(fmaxf(uf[4], 0.f)) | ((u32)f2bf(fmaxf(uf[5], 0.f)) << 16);
  pk.w = (u32)f2bf(fmaxf(uf[6], 0.f)) | ((u32)f2bf(fmaxf(uf[7], 0.f)) << 16);
  *(uint4*)(ub + (size_t)t * 512 + lane * 8) = pk;
#undef FETCH_Z
}

// ---------- kernel 5: logits = ub @ Bt2^T + mb; fused log_softmax epilogue. ----------
__global__ __launch_bounds__(256) void mlp_gemm(
    const u16* __restrict__ ub, const u16* __restrict__ Bt2,
    const float* __restrict__ mb, float* __restrict__ out) {
  const int wid = threadIdx.x >> 6, lane = threadIdx.x & 63;
  const int quad = lane >> 4, l16 = lane & 15;
  const int m0 = blockIdx.x * 64 + wid * 16;

  floatx4 acc[4];
#pragma unroll
  for (int ni = 0; ni < 4; ++ni) acc[ni] = (floatx4){0.f, 0.f, 0.f, 0.f};

#pragma unroll 4
  for (int kk = 0; kk < 512; kk += 32) {
    short8 af = *(const short8*)(ub + (size_t)(m0 + l16) * 512 + kk + quad * 8);
#pragma unroll
    for (int ni = 0; ni < 4; ++ni) {
      short8 bf = *(const short8*)(Bt2 + (size_t)(ni * 16 + l16) * 512 + kk + quad * 8);
      acc[ni] = __builtin_amdgcn_mfma_f32_16x16x32_bf16(af, bf, acc[ni], 0, 0, 0);
    }
  }

#pragma unroll
  for (int r = 0; r < 4; ++r) {
    int t = m0 + quad * 4 + r;
    float v[4];
    float mx = -INFINITY;
#pragma unroll
    for (int ni = 0; ni < 4; ++ni) {
      int c = ni * 16 + l16;
      float lg = (c < NCLS) ? (acc[ni][r] + mb[c]) : -INFINITY;
      v[ni] = lg;
      mx = fmaxf(mx, lg);
    }
    mx = fmaxf(mx, __shfl_xor(mx, 1));
    mx = fmaxf(mx, __shfl_xor(mx, 2));
    mx = fmaxf(mx, __shfl_xor(mx, 4));
    mx = fmaxf(mx, __shfl_xor(mx, 8));
    float se = 0.f;
#pragma unroll
    for (int ni = 0; ni < 4; ++ni) {
      int c = ni * 16 + l16;
      if (c < NCLS) se += expf(v[ni] - mx);
    }
    se += __shfl_xor(se, 1);
    se += __shfl_xor(se, 2);
    se += __shfl_xor(se, 4);
    se += __shfl_xor(se, 8);
    float lse = mx + logf(se);
#pragma unroll
    for (int ni = 0; ni < 4; ++ni) {
      int c = ni * 16 + l16;
      if (c < NCLS) out[(size_t)t * NCLS + c] = v[ni] - lse;
    }
  }
}

// ---------- launch ----------
extern "C" void kernel_launch(void* const* d_in, const int* in_sizes, int n_in,
                              void* d_out, int out_size, void* d_ws, size_t ws_size,
                              hipStream_t stream) {
  const float* x_nb  = (const float*)d_in[0];
  const float* ppr   = (const float*)d_in[1];
  const float* pca_w = (const float*)d_in[2];
  const float* pca_b = (const float*)d_in[3];
  const float* mlp_w = (const float*)d_in[4];
  const float* mlp_b = (const float*)d_in[5];
  const int* row_idx = (const int*)d_in[6];
  const int* col_idx = (const int*)d_in[7];
  float* out = (float*)d_out;

  char* ws = (char*)d_ws;
  // workspace layout (bytes), total ~223 MB (ws is ~819 MB):
  const size_t OFF_BT   = 0;                                  // 512K (Bt, later Bt2)
  const size_t OFF_PPRN = 512 * 1024;                         // E*4 = 512K
  const size_t OFF_OFFS = 1024 * 1024;                        // (T+1)*4
  const size_t OFF_XN   = 1024 * 1024 + 128 * 1024;           // NB*512*2 = 102.4 MB
  const size_t OFF_AB   = OFF_XN + (size_t)NB_N * 512 * 2;    // 100096*512*2 = 102.5 MB
  const size_t OFF_UB   = OFF_AB + (size_t)NTILES * 128 * 512 * 2;  // T*512*2 = 16.8 MB
  u16*   Bt   = (u16*)(ws + OFF_BT);
  u16*   Bt2  = (u16*)(ws + OFF_BT);
  float* pprn = (float*)(ws + OFF_PPRN);
  int*   offs = (int*)(ws + OFF_OFFS);
  u16*   xn   = (u16*)(ws + OFF_XN);
  u16*   Ab   = (u16*)(ws + OFF_AB);
  u16*   ub   = (u16*)(ws + OFF_UB);

  conv_bt<<<1024, 256, 0, stream>>>(pca_w, Bt);
  build_offs<<<512, 256, 0, stream>>>(row_idx, offs);
  ppr_sm<<<64, 256, 0, stream>>>(ppr, offs, pprn);

  conv_a<<<(NTILES * 128 * 128 + 255) / 256, 256, 0, stream>>>(x_nb, Ab);
  gemm_pca<<<dim3(4, NTILES), 256, 0, stream>>>(Ab, Bt, pca_b, xn);
  conv_bt2<<<128, 256, 0, stream>>>(mlp_w, Bt2);  // after gemm (Bt region reuse)

  fused_all<<<T_N, 64, 0, stream>>>(xn, col_idx, offs, pprn, ub);

  mlp_gemm<<<256, 256, 0, stream>>>(ub, Bt2, mlp_b, out);
}

// Round 5
// 559.044 us; speedup vs baseline: 2.7686x; 1.0327x over previous
//
#include <hip/hip_runtime.h>
#include <cstdint>
#include <cstddef>

// Problem constants (fixed by reference file)
#define NB_N 100000
#define E_N  131072
#define T_N  16384
#define D_N  512
#define NCLS 40
#define NTILES 782          // ceil(100000/128); 782*128 = 100096
#define CAPR 12             // register z-cache edges/target (P(deg>12|Poisson(8))~6%)

typedef unsigned short u16;
typedef unsigned int   u32;
typedef __attribute__((ext_vector_type(8))) short  short8;   // 8 bf16 (4 VGPRs)
typedef __attribute__((ext_vector_type(4))) float  floatx4;  // MFMA accumulator

// ---------- bf16 helpers (manual, RNE) ----------
__device__ __forceinline__ u16 f2bf(float f) {
  u32 u = __float_as_uint(f);
  return (u16)((u + 0x7fffu + ((u >> 16) & 1u)) >> 16);
}
__device__ __forceinline__ void unpack8(uint4 z, float* f) {
  f[0] = __uint_as_float(z.x << 16);
  f[1] = __uint_as_float(z.x & 0xffff0000u);
  f[2] = __uint_as_float(z.y << 16);
  f[3] = __uint_as_float(z.y & 0xffff0000u);
  f[4] = __uint_as_float(z.z << 16);
  f[5] = __uint_as_float(z.z & 0xffff0000u);
  f[6] = __uint_as_float(z.w << 16);
  f[7] = __uint_as_float(z.w & 0xffff0000u);
}
__device__ __forceinline__ void gload_lds16(const void* g, void* s) {
  __builtin_amdgcn_global_load_lds(
      (const __attribute__((address_space(1))) unsigned int*)g,
      (__attribute__((address_space(3))) unsigned int*)s, 16, 0, 0);
}

// ---------- kernel 0: transpose+convert pca_w (K,N) f32 -> Bt (N,K) bf16 ----------
__global__ void conv_bt(const float* __restrict__ w, u16* __restrict__ Bt) {
  int i = blockIdx.x * 256 + threadIdx.x;       // i over 512*512, i = n*512+k
  int n = i >> 9, k = i & 511;
  Bt[i] = f2bf(w[k * 512 + n]);
}

// ---------- kernel 0b: transpose+convert mlp_w (512,40) f32 -> Bt2 (64,512) bf16, zero-pad ----
__global__ void conv_bt2(const float* __restrict__ w, u16* __restrict__ Bt2) {
  int i = blockIdx.x * 256 + threadIdx.x;       // 64*512 elements, i = n*512+k
  int n = i >> 9, k = i & 511;
  Bt2[i] = (n < NCLS) ? f2bf(w[k * NCLS + n]) : (u16)0;
}

// ---------- kernel 0c: convert all of x_nb f32 -> Ab bf16 (zero-pad rows >= NB) ----
__global__ void conv_a(const float* __restrict__ A, u16* __restrict__ Ab) {
  int i = blockIdx.x * 256 + threadIdx.x;       // float4 id
  if (i >= NTILES * 128 * 128) return;          // 128 float4 per 512-wide row
  int row = i >> 7;
  float4 v;
  if (row < NB_N) v = ((const float4*)(A + (size_t)row * 512))[i & 127];
  else            v = make_float4(0.f, 0.f, 0.f, 0.f);
  uint2 pk;
  pk.x = (u32)f2bf(v.x) | ((u32)f2bf(v.y) << 16);
  pk.y = (u32)f2bf(v.z) | ((u32)f2bf(v.w) << 16);
  *(uint2*)(Ab + (size_t)i * 4) = pk;
}

// ---------- kernel 1: CSR offsets from sorted row_idx ----------
__global__ void build_offs(const int* __restrict__ rowi, int* __restrict__ offs) {
  int e = blockIdx.x * 256 + threadIdx.x;
  if (e >= E_N) return;
  int r  = rowi[e];
  int rp = (e == 0) ? -1 : rowi[e - 1];
  for (int t = rp + 1; t <= r; ++t) offs[t] = e;
  if (e == E_N - 1)
    for (int t = r + 1; t <= T_N; ++t) offs[t] = E_N;
}

// ---------- kernel 2: segment softmax of ppr ----------
__global__ void ppr_sm(const float* __restrict__ ppr, const int* __restrict__ offs,
                       float* __restrict__ pprn) {
  int t = blockIdx.x * 256 + threadIdx.x;       // T_N threads
  int s = offs[t], en = offs[t + 1];
  if (s >= en) return;
  float m = -INFINITY;
  for (int e = s; e < en; ++e) m = fmaxf(m, ppr[e]);
  float sum = 0.f;
  for (int e = s; e < en; ++e) sum += expf(ppr[e] - m);
  float inv = 1.f / sum;
  for (int e = s; e < en; ++e) pprn[e] = expf(ppr[e] - m) * inv;
}

// ---------- kernel 3: bf16 MFMA GEMM x = relu(Ab @ pca_w + b), per-capsule l2norm,
//            writes xn bf16. 128x128 tile, BK=64, 4 waves, all-DMA staging. ----------
__global__ __launch_bounds__(256) void gemm_pca(
    const u16*   __restrict__ Ab,   // (NTILES*128, 512) bf16
    const u16*   __restrict__ Bt,   // (512,512) bf16, n-major (pre-transposed)
    const float* __restrict__ bias, // (512,)
    u16*         __restrict__ xn) { // (NB,512) bf16, normalized
  __shared__ u16 As[128 * 64];      // 16 KB
  __shared__ u16 Bs[128 * 64];      // 16 KB
  const int tid  = threadIdx.x;
  const int wid  = tid >> 6, lane = tid & 63;
  const int quad = lane >> 4, l16 = lane & 15;
  const int m0 = blockIdx.y * 128;
  const int n0 = blockIdx.x * 128;
  const int wm = (wid >> 1) * 64;
  const int wn = (wid & 1) * 64;
  const u16* Arow = Ab + (size_t)m0 * 512;

  floatx4 acc[4][4];
#pragma unroll
  for (int i = 0; i < 4; ++i)
#pragma unroll
    for (int j = 0; j < 4; ++j) acc[i][j] = (floatx4){0.f, 0.f, 0.f, 0.f};

  for (int k0 = 0; k0 < 512; k0 += 64) {
#pragma unroll
    for (int j = 0; j < 4; ++j) {
      int ci  = j * 256 + wid * 64 + lane;  // chunk id (wave-contiguous)
      int row = ci >> 3, kc = ci & 7;       // 8 chunks per 64-elem row
      gload_lds16(Arow + (size_t)row * 512 + k0 + kc * 8,
                  &As[(size_t)(j * 256 + wid * 64) * 8]);
      gload_lds16(Bt + (size_t)(n0 + row) * 512 + k0 + kc * 8,
                  &Bs[(size_t)(j * 256 + wid * 64) * 8]);
    }
    __syncthreads();
#pragma unroll
    for (int kk = 0; kk < 64; kk += 32) {
      short8 af[4], bf[4];
#pragma unroll
      for (int mi = 0; mi < 4; ++mi)
        af[mi] = *(const short8*)(&As[(wm + mi * 16 + l16) * 64 + kk + quad * 8]);
#pragma unroll
      for (int ni = 0; ni < 4; ++ni)
        bf[ni] = *(const short8*)(&Bs[(wn + ni * 16 + l16) * 64 + kk + quad * 8]);
#pragma unroll
      for (int mi = 0; mi < 4; ++mi)
#pragma unroll
        for (int ni = 0; ni < 4; ++ni)
          acc[mi][ni] = __builtin_amdgcn_mfma_f32_16x16x32_bf16(af[mi], bf[ni],
                                                                acc[mi][ni], 0, 0, 0);
    }
    __syncthreads();
  }

  // epilogue: +bias, relu, per-capsule (64-col) l2norm, store bf16.
#pragma unroll
  for (int mi = 0; mi < 4; ++mi) {
#pragma unroll
    for (int r = 0; r < 4; ++r) {
      int gm = m0 + wm + mi * 16 + quad * 4 + r;
      float v[4];
      float ss = 0.f;
#pragma unroll
      for (int ni = 0; ni < 4; ++ni) {
        int n  = n0 + wn + ni * 16 + l16;
        float x = acc[mi][ni][r] + bias[n];
        x = fmaxf(x, 0.f);
        v[ni] = x;
        ss += x * x;
      }
      ss += __shfl_xor(ss, 1);
      ss += __shfl_xor(ss, 2);
      ss += __shfl_xor(ss, 4);
      ss += __shfl_xor(ss, 8);
      float sc = 1.f / fmaxf(sqrtf(ss), 1e-12f);
      if (gm < NB_N) {
#pragma unroll
        for (int ni = 0; ni < 4; ++ni) {
          int n = n0 + wn + ni * 16 + l16;
          xn[(size_t)gm * 512 + n] = f2bf(v[ni] * sc);
        }
      }
    }
  }
}

// ---------- kernel 4: ALL routing (init + 3 rounds), one target per wave.
//            Fully register-resident: z rows in uint4 zreg[CAPR] (tail edges re-fetch
//            global), capsule-weights P distributed across lanes (owner lane
//            ((j&7)<<3)|cap), moved by shuffles. No LDS, no barriers. ----------
__global__ __launch_bounds__(256, 3) void fused_all(
    const u16* __restrict__ xn, const int* __restrict__ coli,
    const int* __restrict__ offs, const float* __restrict__ pprn,
    u16* __restrict__ ub) {
  const int lane = threadIdx.x & 63;
  const int t = blockIdx.x * 4 + (threadIdx.x >> 6);
  const int s = offs[t], en = offs[t + 1];
  int deg = en - s;
  if (deg > 64) deg = 64;           // Poisson(8): max over 16k targets ~27
  const int cap = lane >> 3;        // capsule owning this lane's 8 dims
  const int slot = lane >> 3, c2 = lane & 7;  // phase-2 ownership coords

  int   mycol = (lane < deg) ? coli[s + lane] : 0;
  float myppr = (lane < deg) ? pprn[s + lane] : 0.f;

  // one-shot gather of the first CAPR edges' z rows into registers (independent loads)
  uint4 zreg[CAPR];
#pragma unroll
  for (int j = 0; j < CAPR; ++j) {
    if (j < deg) {                  // wave-uniform branch
      int c = __shfl(mycol, j);
      zreg[j] = *(const uint4*)(xn + (size_t)c * 512 + lane * 8);
    }
  }

  // init: u0 = sum_e pprn_e * z_e
  float uf[8] = {0.f, 0.f, 0.f, 0.f, 0.f, 0.f, 0.f, 0.f};
#pragma unroll
  for (int j = 0; j < CAPR; ++j) {
    if (j < deg) {
      float w = __shfl(myppr, j);
      float zf[8];
      unpack8(zreg[j], zf);
#pragma unroll
      for (int q = 0; q < 8; ++q) uf[q] += w * zf[q];
    }
  }
  for (int j = CAPR; j < deg; ++j) {  // rare tail (P~6%)
    float w = __shfl(myppr, j);
    int c = __shfl(mycol, j);
    uint4 zz = *(const uint4*)(xn + (size_t)c * 512 + lane * 8);
    float zf[8];
    unpack8(zz, zf);
#pragma unroll
    for (int q = 0; q < 8; ++q) uf[q] += w * zf[q];
  }

  // P[j][c] lives at lane ((j&7)<<3)|c, register Preg[j>>3]
  float Preg[8];

  for (int it = 0; it < 3; ++it) {
    // ---- phase 1: capsule logits d = <u_cap, z_j_cap>, scatter to owner lanes ----
#pragma unroll
    for (int j = 0; j < CAPR; ++j) {
      if (j < deg) {
        float zf[8];
        unpack8(zreg[j], zf);
        float d = uf[0]*zf[0] + uf[1]*zf[1] + uf[2]*zf[2] + uf[3]*zf[3] +
                  uf[4]*zf[4] + uf[5]*zf[5] + uf[6]*zf[6] + uf[7]*zf[7];
        d += __shfl_xor(d, 1);
        d += __shfl_xor(d, 2);
        d += __shfl_xor(d, 4);      // all lanes in 8-group g hold capsule-g sum
        float dc = __shfl(d, (lane & 7) << 3);   // capsule (lane&7)'s sum
        if (slot == (j & 7)) Preg[j >> 3] = dc;  // owner stores (compile-time idx)
      }
    }
    for (int j = CAPR; j < deg; ++j) {  // tail: global re-fetch + runtime reg idx
      int c = __shfl(mycol, j);
      uint4 zz = *(const uint4*)(xn + (size_t)c * 512 + lane * 8);
      float zf[8];
      unpack8(zz, zf);
      float d = uf[0]*zf[0] + uf[1]*zf[1] + uf[2]*zf[2] + uf[3]*zf[3] +
                uf[4]*zf[4] + uf[5]*zf[5] + uf[6]*zf[6] + uf[7]*zf[7];
      d += __shfl_xor(d, 1);
      d += __shfl_xor(d, 2);
      d += __shfl_xor(d, 4);
      float dc = __shfl(d, (lane & 7) << 3);
      if (slot == (j & 7)) {
        int hi = j >> 3;                       // uniform scalar branch chain
        if      (hi == 1) Preg[1] = dc;
        else if (hi == 2) Preg[2] = dc;
        else if (hi == 3) Preg[3] = dc;
        else if (hi == 4) Preg[4] = dc;
        else if (hi == 5) Preg[5] = dc;
        else if (hi == 6) Preg[6] = dc;
        else if (hi == 7) Preg[7] = dc;
      }
    }

    // ---- phase 2: segsm -> 0.5/0.5 blend with pprn -> segsm, all in-register ----
    // lane owns edges j = slot + 8*i (i<8), capsule c2; reduce across slots = xor 8,16,32
    {
      float m1 = -INFINITY;
#pragma unroll
      for (int i = 0; i < 8; ++i)
        m1 = (slot + 8*i < deg) ? fmaxf(m1, Preg[i]) : m1;
      m1 = fmaxf(m1, __shfl_xor(m1, 8));
      m1 = fmaxf(m1, __shfl_xor(m1, 16));
      m1 = fmaxf(m1, __shfl_xor(m1, 32));
      float s1 = 0.f;
#pragma unroll
      for (int i = 0; i < 8; ++i)
        s1 += (slot + 8*i < deg) ? expf(Preg[i] - m1) : 0.f;
      s1 += __shfl_xor(s1, 8);
      s1 += __shfl_xor(s1, 16);
      s1 += __shfl_xor(s1, 32);
      float inv1 = 1.f / s1;
      float m2 = -INFINITY;
#pragma unroll
      for (int i = 0; i < 8; ++i) {
        int j = slot + 8*i;
        if (j < deg) {
          float pj = __shfl(myppr, j);   // per-lane src index (bpermute)
          float v = 0.5f * expf(Preg[i] - m1) * inv1 + 0.5f * pj;
          Preg[i] = v;
          m2 = fmaxf(m2, v);
        }
      }
      m2 = fmaxf(m2, __shfl_xor(m2, 8));
      m2 = fmaxf(m2, __shfl_xor(m2, 16));
      m2 = fmaxf(m2, __shfl_xor(m2, 32));
      float s2 = 0.f;
#pragma unroll
      for (int i = 0; i < 8; ++i)
        s2 += (slot + 8*i < deg) ? expf(Preg[i] - m2) : 0.f;
      s2 += __shfl_xor(s2, 8);
      s2 += __shfl_xor(s2, 16);
      s2 += __shfl_xor(s2, 32);
      float inv2 = 1.f / s2;
#pragma unroll
      for (int i = 0; i < 8; ++i)
        if (slot + 8*i < deg) Preg[i] = expf(Preg[i] - m2) * inv2;
    }

    // ---- phase 3: u_new = sum_e P[e][cap] * z_e (+capsule l2norm except last) ----
    float acc[8] = {0.f, 0.f, 0.f, 0.f, 0.f, 0.f, 0.f, 0.f};
#pragma unroll
    for (int j = 0; j < CAPR; ++j) {
      if (j < deg) {
        float w = __shfl(Preg[j >> 3], ((j & 7) << 3) | cap);
        float zf[8];
        unpack8(zreg[j], zf);
#pragma unroll
        for (int q = 0; q < 8; ++q) acc[q] += w * zf[q];
      }
    }
    for (int j = CAPR; j < deg; ++j) {  // rare tail
      int hi = j >> 3;                  // uniform: pick Preg[hi] via scalar chain
      float pr = Preg[1];
      if      (hi == 2) pr = Preg[2];
      else if (hi == 3) pr = Preg[3];
      else if (hi == 4) pr = Preg[4];
      else if (hi == 5) pr = Preg[5];
      else if (hi == 6) pr = Preg[6];
      else if (hi == 7) pr = Preg[7];
      float w = __shfl(pr, ((j & 7) << 3) | cap);
      int c = __shfl(mycol, j);
      uint4 zz = *(const uint4*)(xn + (size_t)c * 512 + lane * 8);
      float zf[8];
      unpack8(zz, zf);
#pragma unroll
      for (int q = 0; q < 8; ++q) acc[q] += w * zf[q];
    }
    if (it < 2) {
      float ss = 0.f;
#pragma unroll
      for (int q = 0; q < 8; ++q) ss += acc[q] * acc[q];
      ss += __shfl_xor(ss, 1);
      ss += __shfl_xor(ss, 2);
      ss += __shfl_xor(ss, 4);
      float sc = 1.f / fmaxf(sqrtf(ss), 1e-12f);
#pragma unroll
      for (int q = 0; q < 8; ++q) acc[q] *= sc;
    }
#pragma unroll
    for (int q = 0; q < 8; ++q) uf[q] = acc[q];
  }

  // output: ub = bf16(relu(u)) for the MLP GEMM
  uint4 pk;
  pk.x = (u32)f2bf(fmaxf(uf[0], 0.f)) | ((u32)f2bf(fmaxf(uf[1], 0.f)) << 16);
  pk.y = (u32)f2bf(fmaxf(uf[2], 0.f)) | ((u32)f2bf(fmaxf(uf[3], 0.f)) << 16);
  pk.z = (u32)f2bf(fmaxf(uf[4], 0.f)) | ((u32)f2bf(fmaxf(uf[5], 0.f)) << 16);
  pk.w = (u32)f2bf(fmaxf(uf[6], 0.f)) | ((u32)f2bf(fmaxf(uf[7], 0.f)) << 16);
  *(uint4*)(ub + (size_t)t * 512 + lane * 8) = pk;
}

// ---------- kernel 5: logits = ub @ Bt2^T + mb; fused log_softmax epilogue. ----------
__global__ __launch_bounds__(256) void mlp_gemm(
    const u16* __restrict__ ub, const u16* __restrict__ Bt2,
    const float* __restrict__ mb, float* __restrict__ out) {
  const int wid = threadIdx.x >> 6, lane = threadIdx.x & 63;
  const int quad = lane >> 4, l16 = lane & 15;
  const int m0 = blockIdx.x * 64 + wid * 16;

  floatx4 acc[4];
#pragma unroll
  for (int ni = 0; ni < 4; ++ni) acc[ni] = (floatx4){0.f, 0.f, 0.f, 0.f};

#pragma unroll 4
  for (int kk = 0; kk < 512; kk += 32) {
    short8 af = *(const short8*)(ub + (size_t)(m0 + l16) * 512 + kk + quad * 8);
#pragma unroll
    for (int ni = 0; ni < 4; ++ni) {
      short8 bf = *(const short8*)(Bt2 + (size_t)(ni * 16 + l16) * 512 + kk + quad * 8);
      acc[ni] = __builtin_amdgcn_mfma_f32_16x16x32_bf16(af, bf, acc[ni], 0, 0, 0);
    }
  }

#pragma unroll
  for (int r = 0; r < 4; ++r) {
    int t = m0 + quad * 4 + r;
    float v[4];
    float mx = -INFINITY;
#pragma unroll
    for (int ni = 0; ni < 4; ++ni) {
      int c = ni * 16 + l16;
      float lg = (c < NCLS) ? (acc[ni][r] + mb[c]) : -INFINITY;
      v[ni] = lg;
      mx = fmaxf(mx, lg);
    }
    mx = fmaxf(mx, __shfl_xor(mx, 1));
    mx = fmaxf(mx, __shfl_xor(mx, 2));
    mx = fmaxf(mx, __shfl_xor(mx, 4));
    mx = fmaxf(mx, __shfl_xor(mx, 8));
    float se = 0.f;
#pragma unroll
    for (int ni = 0; ni < 4; ++ni) {
      int c = ni * 16 + l16;
      if (c < NCLS) se += expf(v[ni] - mx);
    }
    se += __shfl_xor(se, 1);
    se += __shfl_xor(se, 2);
    se += __shfl_xor(se, 4);
    se += __shfl_xor(se, 8);
    float lse = mx + logf(se);
#pragma unroll
    for (int ni = 0; ni < 4; ++ni) {
      int c = ni * 16 + l16;
      if (c < NCLS) out[(size_t)t * NCLS + c] = v[ni] - lse;
    }
  }
}

// ---------- launch ----------
extern "C" void kernel_launch(void* const* d_in, const int* in_sizes, int n_in,
                              void* d_out, int out_size, void* d_ws, size_t ws_size,
                              hipStream_t stream) {
  const float* x_nb  = (const float*)d_in[0];
  const float* ppr   = (const float*)d_in[1];
  const float* pca_w = (const float*)d_in[2];
  const float* pca_b = (const float*)d_in[3];
  const float* mlp_w = (const float*)d_in[4];
  const float* mlp_b = (const float*)d_in[5];
  const int* row_idx = (const int*)d_in[6];
  const int* col_idx = (const int*)d_in[7];
  float* out = (float*)d_out;

  char* ws = (char*)d_ws;
  // workspace layout (bytes), total ~223 MB (ws is ~819 MB):
  const size_t OFF_BT   = 0;                                  // 512K (Bt, later Bt2)
  const size_t OFF_PPRN = 512 * 1024;                         // E*4 = 512K
  const size_t OFF_OFFS = 1024 * 1024;                        // (T+1)*4
  const size_t OFF_XN   = 1024 * 1024 + 128 * 1024;           // NB*512*2 = 102.4 MB
  const size_t OFF_AB   = OFF_XN + (size_t)NB_N * 512 * 2;    // 100096*512*2 = 102.5 MB
  const size_t OFF_UB   = OFF_AB + (size_t)NTILES * 128 * 512 * 2;  // T*512*2 = 16.8 MB
  u16*   Bt   = (u16*)(ws + OFF_BT);
  u16*   Bt2  = (u16*)(ws + OFF_BT);
  float* pprn = (float*)(ws + OFF_PPRN);
  int*   offs = (int*)(ws + OFF_OFFS);
  u16*   xn   = (u16*)(ws + OFF_XN);
  u16*   Ab   = (u16*)(ws + OFF_AB);
  u16*   ub   = (u16*)(ws + OFF_UB);

  conv_bt<<<1024, 256, 0, stream>>>(pca_w, Bt);
  build_offs<<<512, 256, 0, stream>>>(row_idx, offs);
  ppr_sm<<<64, 256, 0, stream>>>(ppr, offs, pprn);

  conv_a<<<(NTILES * 128 * 128 + 255) / 256, 256, 0, stream>>>(x_nb, Ab);
  gemm_pca<<<dim3(4, NTILES), 256, 0, stream>>>(Ab, Bt, pca_b, xn);
  conv_bt2<<<128, 256, 0, stream>>>(mlp_w, Bt2);  // after gemm (Bt region reuse)

  fused_all<<<T_N / 4, 256, 0, stream>>>(xn, col_idx, offs, pprn, ub);

  mlp_gemm<<<256, 256, 0, stream>>>(ub, Bt2, mlp_b, out);
}

// Round 6
// 539.307 us; speedup vs baseline: 2.8700x; 1.0366x over previous
//
#include <hip/hip_runtime.h>
#include <cstdint>
#include <cstddef>

// Problem constants (fixed by reference file)
#define NB_N 100000
#define E_N  131072
#define T_N  16384
#define D_N  512
#define NCLS 40
#define NTILES 782          // ceil(100000/128); 782*128 = 100096
#define CAPR 12             // register z-cache edges/target (P(deg>12|Poisson(8))~6%)

typedef unsigned short u16;
typedef unsigned int   u32;
typedef __attribute__((ext_vector_type(8))) short  short8;   // 8 bf16 (4 VGPRs)
typedef __attribute__((ext_vector_type(4))) float  floatx4;  // MFMA accumulator

// ---------- bf16 helpers (manual, RNE) ----------
__device__ __forceinline__ u16 f2bf(float f) {
  u32 u = __float_as_uint(f);
  return (u16)((u + 0x7fffu + ((u >> 16) & 1u)) >> 16);
}
__device__ __forceinline__ void unpack8(uint4 z, float* f) {
  f[0] = __uint_as_float(z.x << 16);
  f[1] = __uint_as_float(z.x & 0xffff0000u);
  f[2] = __uint_as_float(z.y << 16);
  f[3] = __uint_as_float(z.y & 0xffff0000u);
  f[4] = __uint_as_float(z.z << 16);
  f[5] = __uint_as_float(z.z & 0xffff0000u);
  f[6] = __uint_as_float(z.w << 16);
  f[7] = __uint_as_float(z.w & 0xffff0000u);
}
__device__ __forceinline__ void gload_lds16(const void* g, void* s) {
  __builtin_amdgcn_global_load_lds(
      (const __attribute__((address_space(1))) unsigned int*)g,
      (__attribute__((address_space(3))) unsigned int*)s, 16, 0, 0);
}

// ---------- kernel 0: transpose+convert pca_w (K,N) f32 -> Bt (N,K) bf16 ----------
__global__ void conv_bt(const float* __restrict__ w, u16* __restrict__ Bt) {
  int i = blockIdx.x * 256 + threadIdx.x;       // i over 512*512, i = n*512+k
  int n = i >> 9, k = i & 511;
  Bt[i] = f2bf(w[k * 512 + n]);
}

// ---------- kernel 0b: transpose+convert mlp_w (512,40) f32 -> Bt2 (64,512) bf16, zero-pad ----
__global__ void conv_bt2(const float* __restrict__ w, u16* __restrict__ Bt2) {
  int i = blockIdx.x * 256 + threadIdx.x;       // 64*512 elements, i = n*512+k
  int n = i >> 9, k = i & 511;
  Bt2[i] = (n < NCLS) ? f2bf(w[k * NCLS + n]) : (u16)0;
}

// ---------- kernel 0c: convert all of x_nb f32 -> Ab bf16 (zero-pad rows >= NB) ----
__global__ void conv_a(const float* __restrict__ A, u16* __restrict__ Ab) {
  int i = blockIdx.x * 256 + threadIdx.x;       // float4 id
  if (i >= NTILES * 128 * 128) return;          // 128 float4 per 512-wide row
  int row = i >> 7;
  float4 v;
  if (row < NB_N) v = ((const float4*)(A + (size_t)row * 512))[i & 127];
  else            v = make_float4(0.f, 0.f, 0.f, 0.f);
  uint2 pk;
  pk.x = (u32)f2bf(v.x) | ((u32)f2bf(v.y) << 16);
  pk.y = (u32)f2bf(v.z) | ((u32)f2bf(v.w) << 16);
  *(uint2*)(Ab + (size_t)i * 4) = pk;
}

// ---------- kernel 1: CSR offsets from sorted row_idx ----------
__global__ void build_offs(const int* __restrict__ rowi, int* __restrict__ offs) {
  int e = blockIdx.x * 256 + threadIdx.x;
  if (e >= E_N) return;
  int r  = rowi[e];
  int rp = (e == 0) ? -1 : rowi[e - 1];
  for (int t = rp + 1; t <= r; ++t) offs[t] = e;
  if (e == E_N - 1)
    for (int t = r + 1; t <= T_N; ++t) offs[t] = E_N;
}

// ---------- kernel 2: segment softmax of ppr ----------
__global__ void ppr_sm(const float* __restrict__ ppr, const int* __restrict__ offs,
                       float* __restrict__ pprn) {
  int t = blockIdx.x * 256 + threadIdx.x;       // T_N threads
  int s = offs[t], en = offs[t + 1];
  if (s >= en) return;
  float m = -INFINITY;
  for (int e = s; e < en; ++e) m = fmaxf(m, ppr[e]);
  float sum = 0.f;
  for (int e = s; e < en; ++e) sum += expf(ppr[e] - m);
  float inv = 1.f / sum;
  for (int e = s; e < en; ++e) pprn[e] = expf(ppr[e] - m) * inv;
}

// ---------- kernel 3: bf16 MFMA GEMM x = relu(Ab @ pca_w + b), per-capsule l2norm,
//            writes xn bf16. 128x128 tile, BK=64, 4 waves, all-DMA staging.
//            R5 fixes: (a) XOR-swizzled LDS k-chunks (source-side permute, DMA dest
//            stays contiguous) -> bank-conflict-free b128 frag reads; (b) epilogue
//            staged through LDS -> full-line xn stores (kills RMW over-fetch);
//            (c) XCD-grouped 1-D grid: 4 n-blocks of one A-tile differ by 8. ----------
__global__ __launch_bounds__(256) void gemm_pca(
    const u16*   __restrict__ Ab,   // (NTILES*128, 512) bf16
    const u16*   __restrict__ Bt,   // (512,512) bf16, n-major (pre-transposed)
    const float* __restrict__ bias, // (512,)
    u16*         __restrict__ xn) { // (NB,512) bf16, normalized
  __shared__ u16 SMEM[2 * 128 * 64];  // 32 KB: As | Bs, reused as out-tile
  u16* As = SMEM;
  u16* Bs = SMEM + 128 * 64;
  const int tid  = threadIdx.x;
  const int wid  = tid >> 6, lane = tid & 63;
  const int quad = lane >> 4, l16 = lane & 15;
  // XCD-grouped decode: b = 32g + 8n + mlow -> mt = 8g+mlow, n. Same-mt blocks
  // differ by 8 in flat id -> same XCD under round-robin -> shared A-tile in L2.
  const int b  = blockIdx.x;
  const int mt = (b & 7) | ((b >> 5) << 3);
  if (mt >= NTILES) return;
  const int m0 = mt * 128;
  const int n0 = ((b >> 3) & 3) * 128;
  const int wm = (wid >> 1) * 64;
  const int wn = (wid & 1) * 64;
  const int sw = l16 & 7;             // per-lane chunk swizzle for frag reads
  const u16* Arow = Ab + (size_t)m0 * 512;

  floatx4 acc[4][4];
#pragma unroll
  for (int i = 0; i < 4; ++i)
#pragma unroll
    for (int j = 0; j < 4; ++j) acc[i][j] = (floatx4){0.f, 0.f, 0.f, 0.f};

  for (int k0 = 0; k0 < 512; k0 += 64) {
    // stage A and B: 1024 16B-chunks each, DMA, source k-chunk XORed by row&7
#pragma unroll
    for (int j = 0; j < 4; ++j) {
      int ci  = j * 256 + wid * 64 + lane;    // chunk id (wave-contiguous dest)
      int row = ci >> 3;
      int kcs = (lane & 7) ^ ((lane >> 3) & 7);  // swizzled source chunk (row&7 == lane>>3)
      gload_lds16(Arow + (size_t)row * 512 + k0 + kcs * 8,
                  &As[(size_t)(j * 256 + wid * 64) * 8]);
      gload_lds16(Bt + (size_t)(n0 + row) * 512 + k0 + kcs * 8,
                  &Bs[(size_t)(j * 256 + wid * 64) * 8]);
    }
    __syncthreads();
#pragma unroll
    for (int kk = 0; kk < 64; kk += 32) {
      short8 af[4], bf[4];
#pragma unroll
      for (int mi = 0; mi < 4; ++mi) {
        int c = (kk >> 3) + quad;
        af[mi] = *(const short8*)(&As[(wm + mi * 16 + l16) * 64 + ((c ^ sw) << 3)]);
      }
#pragma unroll
      for (int ni = 0; ni < 4; ++ni) {
        int c = (kk >> 3) + quad;
        bf[ni] = *(const short8*)(&Bs[(wn + ni * 16 + l16) * 64 + ((c ^ sw) << 3)]);
      }
#pragma unroll
      for (int mi = 0; mi < 4; ++mi)
#pragma unroll
        for (int ni = 0; ni < 4; ++ni)
          acc[mi][ni] = __builtin_amdgcn_mfma_f32_16x16x32_bf16(af[mi], bf[ni],
                                                                acc[mi][ni], 0, 0, 0);
    }
    __syncthreads();
  }

  // epilogue: +bias, relu, per-capsule (64-col) l2norm -> LDS tile -> full-line stores
  u16* Os = SMEM;                     // 128x128 u16 = 32 KB (As/Bs dead)
#pragma unroll
  for (int mi = 0; mi < 4; ++mi) {
#pragma unroll
    for (int r = 0; r < 4; ++r) {
      int lrow = wm + mi * 16 + quad * 4 + r;
      float v[4];
      float ss = 0.f;
#pragma unroll
      for (int ni = 0; ni < 4; ++ni) {
        int n  = n0 + wn + ni * 16 + l16;
        float x = acc[mi][ni][r] + bias[n];
        x = fmaxf(x, 0.f);
        v[ni] = x;
        ss += x * x;
      }
      ss += __shfl_xor(ss, 1);
      ss += __shfl_xor(ss, 2);
      ss += __shfl_xor(ss, 4);
      ss += __shfl_xor(ss, 8);
      float sc = 1.f / fmaxf(sqrtf(ss), 1e-12f);
#pragma unroll
      for (int ni = 0; ni < 4; ++ni)
        Os[lrow * 128 + wn + ni * 16 + l16] = f2bf(v[ni] * sc);
    }
  }
  __syncthreads();
#pragma unroll
  for (int c8 = 0; c8 < 8; ++c8) {    // 2048 16B-chunks, 8 per thread, 1KB/wave lines
    int idx = c8 * 256 + tid;
    int row = idx >> 4, chk = idx & 15;
    int gm = m0 + row;
    if (gm < NB_N) {
      uint4 val = *(const uint4*)(&Os[row * 128 + chk * 8]);
      *(uint4*)(xn + (size_t)gm * 512 + n0 + chk * 8) = val;
    }
  }
}

// ---------- kernel 4: ALL routing (init + 3 rounds), one target per wave.
//            Fully register-resident: z rows in uint4 zreg[CAPR] (tail edges re-fetch
//            global), capsule-weights P distributed across lanes (owner lane
//            ((j&7)<<3)|cap), moved by shuffles. No LDS, no barriers. ----------
__global__ __launch_bounds__(256, 3) void fused_all(
    const u16* __restrict__ xn, const int* __restrict__ coli,
    const int* __restrict__ offs, const float* __restrict__ pprn,
    u16* __restrict__ ub) {
  const int lane = threadIdx.x & 63;
  const int t = blockIdx.x * 4 + (threadIdx.x >> 6);
  const int s = offs[t], en = offs[t + 1];
  int deg = en - s;
  if (deg > 64) deg = 64;           // Poisson(8): max over 16k targets ~27
  const int cap = lane >> 3;        // capsule owning this lane's 8 dims
  const int slot = lane >> 3;

  int   mycol = (lane < deg) ? coli[s + lane] : 0;
  float myppr = (lane < deg) ? pprn[s + lane] : 0.f;

  // one-shot gather of the first CAPR edges' z rows into registers (independent loads)
  uint4 zreg[CAPR];
#pragma unroll
  for (int j = 0; j < CAPR; ++j) {
    if (j < deg) {                  // wave-uniform branch
      int c = __shfl(mycol, j);
      zreg[j] = *(const uint4*)(xn + (size_t)c * 512 + lane * 8);
    }
  }

  // init: u0 = sum_e pprn_e * z_e
  float uf[8] = {0.f, 0.f, 0.f, 0.f, 0.f, 0.f, 0.f, 0.f};
#pragma unroll
  for (int j = 0; j < CAPR; ++j) {
    if (j < deg) {
      float w = __shfl(myppr, j);
      float zf[8];
      unpack8(zreg[j], zf);
#pragma unroll
      for (int q = 0; q < 8; ++q) uf[q] += w * zf[q];
    }
  }
  for (int j = CAPR; j < deg; ++j) {  // rare tail (P~6%)
    float w = __shfl(myppr, j);
    int c = __shfl(mycol, j);
    uint4 zz = *(const uint4*)(xn + (size_t)c * 512 + lane * 8);
    float zf[8];
    unpack8(zz, zf);
#pragma unroll
    for (int q = 0; q < 8; ++q) uf[q] += w * zf[q];
  }

  // P[j][c] lives at lane ((j&7)<<3)|c, register Preg[j>>3]
  float Preg[8];

  for (int it = 0; it < 3; ++it) {
    // ---- phase 1: capsule logits d = <u_cap, z_j_cap>, scatter to owner lanes ----
#pragma unroll
    for (int j = 0; j < CAPR; ++j) {
      if (j < deg) {
        float zf[8];
        unpack8(zreg[j], zf);
        float d = uf[0]*zf[0] + uf[1]*zf[1] + uf[2]*zf[2] + uf[3]*zf[3] +
                  uf[4]*zf[4] + uf[5]*zf[5] + uf[6]*zf[6] + uf[7]*zf[7];
        d += __shfl_xor(d, 1);
        d += __shfl_xor(d, 2);
        d += __shfl_xor(d, 4);      // all lanes in 8-group g hold capsule-g sum
        float dc = __shfl(d, (lane & 7) << 3);   // capsule (lane&7)'s sum
        if (slot == (j & 7)) Preg[j >> 3] = dc;  // owner stores (compile-time idx)
      }
    }
    for (int j = CAPR; j < deg; ++j) {  // tail: global re-fetch + runtime reg idx
      int c = __shfl(mycol, j);
      uint4 zz = *(const uint4*)(xn + (size_t)c * 512 + lane * 8);
      float zf[8];
      unpack8(zz, zf);
      float d = uf[0]*zf[0] + uf[1]*zf[1] + uf[2]*zf[2] + uf[3]*zf[3] +
                uf[4]*zf[4] + uf[5]*zf[5] + uf[6]*zf[6] + uf[7]*zf[7];
      d += __shfl_xor(d, 1);
      d += __shfl_xor(d, 2);
      d += __shfl_xor(d, 4);
      float dc = __shfl(d, (lane & 7) << 3);
      if (slot == (j & 7)) {
        int hi = j >> 3;                       // uniform scalar branch chain
        if      (hi == 1) Preg[1] = dc;
        else if (hi == 2) Preg[2] = dc;
        else if (hi == 3) Preg[3] = dc;
        else if (hi == 4) Preg[4] = dc;
        else if (hi == 5) Preg[5] = dc;
        else if (hi == 6) Preg[6] = dc;
        else if (hi == 7) Preg[7] = dc;
      }
    }

    // ---- phase 2: segsm -> 0.5/0.5 blend with pprn -> segsm, all in-register ----
    {
      float m1 = -INFINITY;
#pragma unroll
      for (int i = 0; i < 8; ++i)
        m1 = (slot + 8*i < deg) ? fmaxf(m1, Preg[i]) : m1;
      m1 = fmaxf(m1, __shfl_xor(m1, 8));
      m1 = fmaxf(m1, __shfl_xor(m1, 16));
      m1 = fmaxf(m1, __shfl_xor(m1, 32));
      float s1 = 0.f;
#pragma unroll
      for (int i = 0; i < 8; ++i)
        s1 += (slot + 8*i < deg) ? expf(Preg[i] - m1) : 0.f;
      s1 += __shfl_xor(s1, 8);
      s1 += __shfl_xor(s1, 16);
      s1 += __shfl_xor(s1, 32);
      float inv1 = 1.f / s1;
      float m2 = -INFINITY;
#pragma unroll
      for (int i = 0; i < 8; ++i) {
        int j = slot + 8*i;
        if (j < deg) {
          float pj = __shfl(myppr, j);   // per-lane src index (bpermute)
          float v = 0.5f * expf(Preg[i] - m1) * inv1 + 0.5f * pj;
          Preg[i] = v;
          m2 = fmaxf(m2, v);
        }
      }
      m2 = fmaxf(m2, __shfl_xor(m2, 8));
      m2 = fmaxf(m2, __shfl_xor(m2, 16));
      m2 = fmaxf(m2, __shfl_xor(m2, 32));
      float s2 = 0.f;
#pragma unroll
      for (int i = 0; i < 8; ++i)
        s2 += (slot + 8*i < deg) ? expf(Preg[i] - m2) : 0.f;
      s2 += __shfl_xor(s2, 8);
      s2 += __shfl_xor(s2, 16);
      s2 += __shfl_xor(s2, 32);
      float inv2 = 1.f / s2;
#pragma unroll
      for (int i = 0; i < 8; ++i)
        if (slot + 8*i < deg) Preg[i] = expf(Preg[i] - m2) * inv2;
    }

    // ---- phase 3: u_new = sum_e P[e][cap] * z_e (+capsule l2norm except last) ----
    float acc[8] = {0.f, 0.f, 0.f, 0.f, 0.f, 0.f, 0.f, 0.f};
#pragma unroll
    for (int j = 0; j < CAPR; ++j) {
      if (j < deg) {
        float w = __shfl(Preg[j >> 3], ((j & 7) << 3) | cap);
        float zf[8];
        unpack8(zreg[j], zf);
#pragma unroll
        for (int q = 0; q < 8; ++q) acc[q] += w * zf[q];
      }
    }
    for (int j = CAPR; j < deg; ++j) {  // rare tail
      int hi = j >> 3;                  // uniform: pick Preg[hi] via scalar chain
      float pr = Preg[1];
      if      (hi == 2) pr = Preg[2];
      else if (hi == 3) pr = Preg[3];
      else if (hi == 4) pr = Preg[4];
      else if (hi == 5) pr = Preg[5];
      else if (hi == 6) pr = Preg[6];
      else if (hi == 7) pr = Preg[7];
      float w = __shfl(pr, ((j & 7) << 3) | cap);
      int c = __shfl(mycol, j);
      uint4 zz = *(const uint4*)(xn + (size_t)c * 512 + lane * 8);
      float zf[8];
      unpack8(zz, zf);
#pragma unroll
      for (int q = 0; q < 8; ++q) acc[q] += w * zf[q];
    }
    if (it < 2) {
      float ss = 0.f;
#pragma unroll
      for (int q = 0; q < 8; ++q) ss += acc[q] * acc[q];
      ss += __shfl_xor(ss, 1);
      ss += __shfl_xor(ss, 2);
      ss += __shfl_xor(ss, 4);
      float sc = 1.f / fmaxf(sqrtf(ss), 1e-12f);
#pragma unroll
      for (int q = 0; q < 8; ++q) acc[q] *= sc;
    }
#pragma unroll
    for (int q = 0; q < 8; ++q) uf[q] = acc[q];
  }

  // output: ub = bf16(relu(u)) for the MLP GEMM
  uint4 pk;
  pk.x = (u32)f2bf(fmaxf(uf[0], 0.f)) | ((u32)f2bf(fmaxf(uf[1], 0.f)) << 16);
  pk.y = (u32)f2bf(fmaxf(uf[2], 0.f)) | ((u32)f2bf(fmaxf(uf[3], 0.f)) << 16);
  pk.z = (u32)f2bf(fmaxf(uf[4], 0.f)) | ((u32)f2bf(fmaxf(uf[5], 0.f)) << 16);
  pk.w = (u32)f2bf(fmaxf(uf[6], 0.f)) | ((u32)f2bf(fmaxf(uf[7], 0.f)) << 16);
  *(uint4*)(ub + (size_t)t * 512 + lane * 8) = pk;
}

// ---------- kernel 5: logits = ub @ Bt2^T + mb; fused log_softmax epilogue. ----------
__global__ __launch_bounds__(256) void mlp_gemm(
    const u16* __restrict__ ub, const u16* __restrict__ Bt2,
    const float* __restrict__ mb, float* __restrict__ out) {
  const int wid = threadIdx.x >> 6, lane = threadIdx.x & 63;
  const int quad = lane >> 4, l16 = lane & 15;
  const int m0 = blockIdx.x * 64 + wid * 16;

  floatx4 acc[4];
#pragma unroll
  for (int ni = 0; ni < 4; ++ni) acc[ni] = (floatx4){0.f, 0.f, 0.f, 0.f};

#pragma unroll 4
  for (int kk = 0; kk < 512; kk += 32) {
    short8 af = *(const short8*)(ub + (size_t)(m0 + l16) * 512 + kk + quad * 8);
#pragma unroll
    for (int ni = 0; ni < 4; ++ni) {
      short8 bf = *(const short8*)(Bt2 + (size_t)(ni * 16 + l16) * 512 + kk + quad * 8);
      acc[ni] = __builtin_amdgcn_mfma_f32_16x16x32_bf16(af, bf, acc[ni], 0, 0, 0);
    }
  }

#pragma unroll
  for (int r = 0; r < 4; ++r) {
    int t = m0 + quad * 4 + r;
    float v[4];
    float mx = -INFINITY;
#pragma unroll
    for (int ni = 0; ni < 4; ++ni) {
      int c = ni * 16 + l16;
      float lg = (c < NCLS) ? (acc[ni][r] + mb[c]) : -INFINITY;
      v[ni] = lg;
      mx = fmaxf(mx, lg);
    }
    mx = fmaxf(mx, __shfl_xor(mx, 1));
    mx = fmaxf(mx, __shfl_xor(mx, 2));
    mx = fmaxf(mx, __shfl_xor(mx, 4));
    mx = fmaxf(mx, __shfl_xor(mx, 8));
    float se = 0.f;
#pragma unroll
    for (int ni = 0; ni < 4; ++ni) {
      int c = ni * 16 + l16;
      if (c < NCLS) se += expf(v[ni] - mx);
    }
    se += __shfl_xor(se, 1);
    se += __shfl_xor(se, 2);
    se += __shfl_xor(se, 4);
    se += __shfl_xor(se, 8);
    float lse = mx + logf(se);
#pragma unroll
    for (int ni = 0; ni < 4; ++ni) {
      int c = ni * 16 + l16;
      if (c < NCLS) out[(size_t)t * NCLS + c] = v[ni] - lse;
    }
  }
}

// ---------- launch ----------
extern "C" void kernel_launch(void* const* d_in, const int* in_sizes, int n_in,
                              void* d_out, int out_size, void* d_ws, size_t ws_size,
                              hipStream_t stream) {
  const float* x_nb  = (const float*)d_in[0];
  const float* ppr   = (const float*)d_in[1];
  const float* pca_w = (const float*)d_in[2];
  const float* pca_b = (const float*)d_in[3];
  const float* mlp_w = (const float*)d_in[4];
  const float* mlp_b = (const float*)d_in[5];
  const int* row_idx = (const int*)d_in[6];
  const int* col_idx = (const int*)d_in[7];
  float* out = (float*)d_out;

  char* ws = (char*)d_ws;
  // workspace layout (bytes), total ~223 MB (ws is ~819 MB):
  const size_t OFF_BT   = 0;                                  // 512K (Bt, later Bt2)
  const size_t OFF_PPRN = 512 * 1024;                         // E*4 = 512K
  const size_t OFF_OFFS = 1024 * 1024;                        // (T+1)*4
  const size_t OFF_XN   = 1024 * 1024 + 128 * 1024;           // NB*512*2 = 102.4 MB
  const size_t OFF_AB   = OFF_XN + (size_t)NB_N * 512 * 2;    // 100096*512*2 = 102.5 MB
  const size_t OFF_UB   = OFF_AB + (size_t)NTILES * 128 * 512 * 2;  // T*512*2 = 16.8 MB
  u16*   Bt   = (u16*)(ws + OFF_BT);
  u16*   Bt2  = (u16*)(ws + OFF_BT);
  float* pprn = (float*)(ws + OFF_PPRN);
  int*   offs = (int*)(ws + OFF_OFFS);
  u16*   xn   = (u16*)(ws + OFF_XN);
  u16*   Ab   = (u16*)(ws + OFF_AB);
  u16*   ub   = (u16*)(ws + OFF_UB);

  conv_bt<<<1024, 256, 0, stream>>>(pca_w, Bt);
  build_offs<<<512, 256, 0, stream>>>(row_idx, offs);
  ppr_sm<<<64, 256, 0, stream>>>(ppr, offs, pprn);

  conv_a<<<(NTILES * 128 * 128 + 255) / 256, 256, 0, stream>>>(x_nb, Ab);
  // 98 groups of 32 blocks: group g covers m-tiles 8g..8g+7 x all 4 n (8 idle blocks)
  gemm_pca<<<98 * 32, 256, 0, stream>>>(Ab, Bt, pca_b, xn);
  conv_bt2<<<128, 256, 0, stream>>>(mlp_w, Bt2);  // after gemm (Bt region reuse)

  fused_all<<<T_N / 4, 256, 0, stream>>>(xn, col_idx, offs, pprn, ub);

  mlp_gemm<<<256, 256, 0, stream>>>(ub, Bt2, mlp_b, out);
}